// Round 5
// baseline (468.831 us; speedup 1.0000x reference)
//
#include <hip/hip_runtime.h>
#include <hip/hip_bf16.h>

typedef __bf16 bf16_t;
typedef bf16_t bf16x8 __attribute__((ext_vector_type(8)));
typedef bf16_t bf16x4 __attribute__((ext_vector_type(4)));
typedef float  f32x4  __attribute__((ext_vector_type(4)));

#define LDC 104   // stride (bf16 elems) for 96-wide tiles
#define LDT 72    // stride for vT token dim
#define LDP 70    // stride for P token dim
#define LDG 392   // stride for fc2 weights [96][392]

// ws layout (bytes)
#define WS_WQ    0
#define WS_WK    19968
#define WS_WV    39936
#define WS_WP    59904
#define WS_FC1   79872      // [384][104] bf16
#define WS_FC2   159744     // [96][392] bf16 (contiguous after FC1)
#define WS_BIAS  235008     // [3][64 row][16 lr][4 f] f32 : 16*sigmoid(cpb bias), f4-transposed
#define WS_TBL   284160     // [225][3] f32 raw cpb table

__device__ __forceinline__ f32x4 mfma16(bf16x8 a, bf16x8 b, f32x4 c) {
    return __builtin_amdgcn_mfma_f32_16x16x32_bf16(a, b, c, 0, 0, 0);
}

__device__ __forceinline__ float cpbf(int v) {   // v in -7..7
    float x = (float)v * (8.0f / 7.0f);
    float l = log2f(fabsf(x) + 1.0f) * (1.0f / 3.0f);
    return x < 0.f ? -l : l;
}

__device__ __forceinline__ int regcnt(int t, int hw, int ww) {
    int r = t >> 3, c = t & 7;
    int rr = (hw == 31) ? (r < 4 ? 1 : 2) : 0;
    int cc = (ww == 31) ? (c < 4 ? 1 : 2) : 0;
    return rr * 3 + cc;
}

__device__ __forceinline__ uint32_t pk2(float lo, float hi) {
    union { bf16_t h[2]; uint32_t u; } z;
    z.h[0] = (bf16_t)lo; z.h[1] = (bf16_t)hi;
    return z.u;
}

// ---------------- k0a: CPB table — one WAVE per entry ----------------
__global__ __launch_bounds__(256) void k0a_cpb(
    const float* __restrict__ cw1, const float* __restrict__ cb1,
    const float* __restrict__ cw2, char* __restrict__ ws)
{
    const int wv = threadIdx.x >> 6, lane = threadIdx.x & 63;
    const int e = blockIdx.x * 4 + wv;
    if (e >= 225) return;
    int ia = e / 15, ib = e % 15;
    float c0 = cpbf(ia - 7), c1 = cpbf(ib - 7);
    float a0 = 0.f, a1 = 0.f, a2 = 0.f;
    #pragma unroll
    for (int c = 0; c < 8; ++c) {
        int j = c * 64 + lane;
        float h = fmaf(c0, cw1[j], fmaf(c1, cw1[512 + j], cb1[j]));
        h = fmaxf(h, 0.f);
        a0 = fmaf(h, cw2[j * 3 + 0], a0);
        a1 = fmaf(h, cw2[j * 3 + 1], a1);
        a2 = fmaf(h, cw2[j * 3 + 2], a2);
    }
    #pragma unroll
    for (int m = 1; m < 64; m <<= 1) {
        a0 += __shfl_xor(a0, m);
        a1 += __shfl_xor(a1, m);
        a2 += __shfl_xor(a2, m);
    }
    if (lane == 0) {
        float* tbl = (float*)(ws + WS_TBL);
        tbl[e * 3 + 0] = a0; tbl[e * 3 + 1] = a1; tbl[e * 3 + 2] = a2;
    }
}

// ---------------- k0w: weight repack (blocks 0..53) + bias expand (blocks 54..77) ----------------
__global__ __launch_bounds__(512) void k0w_prep(
    const float* __restrict__ qw, const float* __restrict__ kw,
    const float* __restrict__ vw, const float* __restrict__ pw,
    const float* __restrict__ fc1w, const float* __restrict__ fc2w,
    char* __restrict__ ws)
{
    int tid = threadIdx.x;
    if (blockIdx.x < 54) {
        int rid = blockIdx.x * 512 + tid;            // 0..27647, float4-coalesced reads
        if (rid < 9216) {                            // q,k,v,proj: [96 in][96 out] -> [out][in]
            int which = rid / 2304, r = rid % 2304;
            int i = r / 24, o4 = r % 24;
            const float* src = which == 0 ? qw : which == 1 ? kw : which == 2 ? vw : pw;
            float4 u = *(const float4*)(src + i * 96 + 4 * o4);
            bf16_t* dst = (bf16_t*)(ws + WS_WQ + which * 19968);
            dst[(4 * o4 + 0) * LDC + i] = (bf16_t)u.x;
            dst[(4 * o4 + 1) * LDC + i] = (bf16_t)u.y;
            dst[(4 * o4 + 2) * LDC + i] = (bf16_t)u.z;
            dst[(4 * o4 + 3) * LDC + i] = (bf16_t)u.w;
        } else if (rid < 18432) {                    // fc1: [96][384] -> [384][104]
            int r = rid - 9216;
            int i = r / 96, m4 = r % 96;
            float4 u = *(const float4*)(fc1w + i * 384 + 4 * m4);
            bf16_t* dst = (bf16_t*)(ws + WS_FC1);
            dst[(4 * m4 + 0) * LDC + i] = (bf16_t)u.x;
            dst[(4 * m4 + 1) * LDC + i] = (bf16_t)u.y;
            dst[(4 * m4 + 2) * LDC + i] = (bf16_t)u.z;
            dst[(4 * m4 + 3) * LDC + i] = (bf16_t)u.w;
        } else {                                     // fc2: [384][96] -> [96][392]
            int r = rid - 18432;
            int g = r / 24, o4 = r % 24;
            float4 u = *(const float4*)(fc2w + g * 96 + 4 * o4);
            bf16_t* dst = (bf16_t*)(ws + WS_FC2);
            dst[(4 * o4 + 0) * LDG + g] = (bf16_t)u.x;
            dst[(4 * o4 + 1) * LDG + g] = (bf16_t)u.y;
            dst[(4 * o4 + 2) * LDG + g] = (bf16_t)u.z;
            dst[(4 * o4 + 3) * LDG + g] = (bf16_t)u.w;
        }
    } else {
        int e = (blockIdx.x - 54) * 512 + tid;       // 0..12287 (h, row n, col m)
        if (e < 12288) {
            const float* tbl = (const float*)(ws + WS_TBL);
            float* bias = (float*)(ws + WS_BIAS);
            int h = e >> 12, nm = e & 4095, n = nm >> 6, m = nm & 63;
            int dr = (n >> 3) - (m >> 3) + 7, dc = (n & 7) - (m & 7) + 7;
            float t = tbl[(dr * 15 + dc) * 3 + h];
            // f4-transposed layout: [h][row][m&15][m>>4]
            bias[(h << 12) | (n << 6) | ((m & 15) << 2) | (m >> 4)] = 16.f / (1.f + __expf(-t));
        }
    }
}

// ---------------- Kernel A: fused window attention -> hs (into d_out) ----------------
__global__ __launch_bounds__(256, 3) void kA_attn(
    const float* __restrict__ hidden, const float* __restrict__ tv,
    const float* __restrict__ qb, const float* __restrict__ vb,
    const float* __restrict__ pb, const float* __restrict__ lsc,
    const float* __restrict__ lnww, const float* __restrict__ lnwb,
    const float* __restrict__ lnbw, const float* __restrict__ lnbb,
    const char* __restrict__ ws, float* __restrict__ hs)
{
    __shared__ __align__(16) char sm[40704];
    bf16_t* vT   = (bf16_t*)(sm + 0);         // [96][72]   = 13824
    bf16_t* qn   = (bf16_t*)(sm + 13824);     // [64][104]  = 13312
    bf16_t* kn   = (bf16_t*)(sm + 27136);     // [64][104]  = 13312
    bf16_t* P    = (bf16_t*)(sm + 13824);     // [3][64][70], overlays qn+kn (after B2)
    bf16_t* ctxb = (bf16_t*)(sm + 0);         // [64][104], overlays vT (after B4)

    const int tid = threadIdx.x;
    const int wv = tid >> 6, lane = tid & 63, lg = lane >> 4, lr = lane & 15;
    const int wid = blockIdx.x;
    const int bat = wid >> 10, wim = wid & 1023, hw = wim >> 5, wwi = wim & 31;

    // ---- phase 1: QKV ----
    {
        bf16x8 af[3];
        {
            int tok = 16 * wv + lr;
            int gr = ((hw << 3) + (tok >> 3) + 4) & 255;
            int gc = ((wwi << 3) + (tok & 7) + 4) & 255;
            const float* xb = hidden + (((size_t)bat << 16) + (gr << 8) + gc) * 96;
            #pragma unroll
            for (int ks = 0; ks < 3; ++ks) {
                float4 u0 = *(const float4*)(xb + 32 * ks + 8 * lg);
                float4 u1 = *(const float4*)(xb + 32 * ks + 8 * lg + 4);
                bf16x8 f;
                f[0] = (bf16_t)u0.x; f[1] = (bf16_t)u0.y; f[2] = (bf16_t)u0.z; f[3] = (bf16_t)u0.w;
                f[4] = (bf16_t)u1.x; f[5] = (bf16_t)u1.y; f[6] = (bf16_t)u1.z; f[7] = (bf16_t)u1.w;
                af[ks] = f;
            }
        }
        const bf16_t* Wq = (const bf16_t*)(ws + WS_WQ);
        const bf16_t* Wk = (const bf16_t*)(ws + WS_WK);
        const bf16_t* Wv = (const bf16_t*)(ws + WS_WV);

        {   // Q
            bf16x8 wf[6][3];
            #pragma unroll
            for (int n = 0; n < 6; ++n)
                #pragma unroll
                for (int ks = 0; ks < 3; ++ks)
                    wf[n][ks] = *(const bf16x8*)(Wq + (16 * n + lr) * LDC + 32 * ks + 8 * lg);
            f32x4 acc[6];
            #pragma unroll
            for (int n = 0; n < 6; ++n) {
                f32x4 a = {0.f,0.f,0.f,0.f};
                #pragma unroll
                for (int ks = 0; ks < 3; ++ks) a = mfma16(af[ks], wf[n][ks], a);
                float bq = qb[16 * n + lr];
                #pragma unroll
                for (int j = 0; j < 4; ++j) a[j] += bq;
                acc[n] = a;
            }
            #pragma unroll
            for (int h = 0; h < 3; ++h)
                #pragma unroll
                for (int j = 0; j < 4; ++j) {
                    float s = acc[2*h][j] * acc[2*h][j] + acc[2*h+1][j] * acc[2*h+1][j];
                    s += __shfl_xor(s, 1); s += __shfl_xor(s, 2); s += __shfl_xor(s, 4); s += __shfl_xor(s, 8);
                    float inv = 1.f / fmaxf(sqrtf(s), 1e-12f);
                    int row = 16 * wv + 4 * lg + j;
                    qn[row * LDC + 32 * h + lr]      = (bf16_t)(acc[2*h][j] * inv);
                    qn[row * LDC + 32 * h + 16 + lr] = (bf16_t)(acc[2*h+1][j] * inv);
                }
        }
        {   // K
            bf16x8 wf[6][3];
            #pragma unroll
            for (int n = 0; n < 6; ++n)
                #pragma unroll
                for (int ks = 0; ks < 3; ++ks)
                    wf[n][ks] = *(const bf16x8*)(Wk + (16 * n + lr) * LDC + 32 * ks + 8 * lg);
            f32x4 acc[6];
            #pragma unroll
            for (int n = 0; n < 6; ++n) {
                f32x4 a = {0.f,0.f,0.f,0.f};
                #pragma unroll
                for (int ks = 0; ks < 3; ++ks) a = mfma16(af[ks], wf[n][ks], a);
                acc[n] = a;
            }
            #pragma unroll
            for (int h = 0; h < 3; ++h)
                #pragma unroll
                for (int j = 0; j < 4; ++j) {
                    float s = acc[2*h][j] * acc[2*h][j] + acc[2*h+1][j] * acc[2*h+1][j];
                    s += __shfl_xor(s, 1); s += __shfl_xor(s, 2); s += __shfl_xor(s, 4); s += __shfl_xor(s, 8);
                    float inv = 1.f / fmaxf(sqrtf(s), 1e-12f);
                    int row = 16 * wv + 4 * lg + j;
                    kn[row * LDC + 32 * h + lr]      = (bf16_t)(acc[2*h][j] * inv);
                    kn[row * LDC + 32 * h + 16 + lr] = (bf16_t)(acc[2*h+1][j] * inv);
                }
        }
        {   // V (store transposed)
            bf16x8 wf[6][3];
            #pragma unroll
            for (int n = 0; n < 6; ++n)
                #pragma unroll
                for (int ks = 0; ks < 3; ++ks)
                    wf[n][ks] = *(const bf16x8*)(Wv + (16 * n + lr) * LDC + 32 * ks + 8 * lg);
            #pragma unroll
            for (int n = 0; n < 6; ++n) {
                f32x4 a = {0.f,0.f,0.f,0.f};
                #pragma unroll
                for (int ks = 0; ks < 3; ++ks) a = mfma16(af[ks], wf[n][ks], a);
                float bv_ = vb[16 * n + lr];
                bf16x4 pk;
                #pragma unroll
                for (int j = 0; j < 4; ++j) pk[j] = (bf16_t)(a[j] + bv_);
                *(bf16x4*)(vT + (16 * n + lr) * LDT + 16 * wv + 4 * lg) = pk;
            }
        }
    }
    __syncthreads();                                         // B1

    // ---- phase 2: S = qn@kn^T (+bias+mask), softmax, write P ----
    {
        float br[3][4][4];
        const float* biasT = (const float*)(ws + WS_BIAS);
        #pragma unroll
        for (int h = 0; h < 3; ++h)
            #pragma unroll
            for (int j = 0; j < 4; ++j) {
                float4 u = *(const float4*)(biasT + (h << 12) + ((16 * wv + 4 * lg + j) << 6) + (lr << 2));
                br[h][0][j] = u.x; br[h][1][j] = u.y; br[h][2][j] = u.z; br[h][3][j] = u.w;
            }

        f32x4 s[3][4];
        #pragma unroll
        for (int h = 0; h < 3; ++h) {
            bf16x8 aq = *(const bf16x8*)(qn + (16 * wv + lr) * LDC + 32 * h + 8 * lg);
            bf16x8 bk[4];
            #pragma unroll
            for (int f = 0; f < 4; ++f)
                bk[f] = *(const bf16x8*)(kn + (16 * f + lr) * LDC + 32 * h + 8 * lg);
            #pragma unroll
            for (int f = 0; f < 4; ++f) {
                f32x4 z = {0.f,0.f,0.f,0.f};
                s[h][f] = mfma16(aq, bk[f], z);
            }
        }
        __syncthreads();                                     // B2

        float ls[3];
        #pragma unroll
        for (int h = 0; h < 3; ++h) ls[h] = __expf(fminf(lsc[h], 4.6051702f));
        int cntm[4], cnti[4];
        #pragma unroll
        for (int f = 0; f < 4; ++f) cntm[f] = regcnt(16 * f + lr, hw, wwi);
        #pragma unroll
        for (int j = 0; j < 4; ++j) cnti[j] = regcnt(16 * wv + 4 * lg + j, hw, wwi);
        #pragma unroll
        for (int h = 0; h < 3; ++h) {
            #pragma unroll
            for (int f = 0; f < 4; ++f)
                #pragma unroll
                for (int j = 0; j < 4; ++j) {
                    float mk = (cnti[j] != cntm[f]) ? -100.f : 0.f;
                    s[h][f][j] = fmaf(s[h][f][j], ls[h], br[h][f][j] + mk);
                }
            #pragma unroll
            for (int j = 0; j < 4; ++j) {
                float mx = fmaxf(fmaxf(s[h][0][j], s[h][1][j]), fmaxf(s[h][2][j], s[h][3][j]));
                mx = fmaxf(mx, __shfl_xor(mx, 1)); mx = fmaxf(mx, __shfl_xor(mx, 2));
                mx = fmaxf(mx, __shfl_xor(mx, 4)); mx = fmaxf(mx, __shfl_xor(mx, 8));
                float sum = 0.f;
                #pragma unroll
                for (int f = 0; f < 4; ++f) { float e = __expf(s[h][f][j] - mx); s[h][f][j] = e; sum += e; }
                sum += __shfl_xor(sum, 1); sum += __shfl_xor(sum, 2); sum += __shfl_xor(sum, 4); sum += __shfl_xor(sum, 8);
                float inv = 1.f / sum;
                int row = 16 * wv + 4 * lg + j;
                #pragma unroll
                for (int f = 0; f < 4; ++f)
                    P[h * 64 * LDP + row * LDP + 16 * f + lr] = (bf16_t)(s[h][f][j] * inv);
            }
        }
    }
    __syncthreads();                                         // B3

    // ---- phase 3: ctx = P@V ----
    {
        f32x4 ctx[6];
        #pragma unroll
        for (int t = 0; t < 6; ++t) { f32x4 z = {0.f,0.f,0.f,0.f}; ctx[t] = z; }
        bf16x8 ap[3][2], bv2[3][2][2];
        #pragma unroll
        for (int h = 0; h < 3; ++h)
            #pragma unroll
            for (int ks = 0; ks < 2; ++ks) {
                ap[h][ks] = *(const bf16x8*)(P + h * 64 * LDP + (16 * wv + lr) * LDP + 32 * ks + 8 * lg);
                #pragma unroll
                for (int dt = 0; dt < 2; ++dt)
                    bv2[h][dt][ks] = *(const bf16x8*)(vT + (32 * h + 16 * dt + lr) * LDT + 32 * ks + 8 * lg);
            }
        #pragma unroll
        for (int h = 0; h < 3; ++h)
            #pragma unroll
            for (int ks = 0; ks < 2; ++ks)
                #pragma unroll
                for (int dt = 0; dt < 2; ++dt)
                    ctx[2 * h + dt] = mfma16(ap[h][ks], bv2[h][dt][ks], ctx[2 * h + dt]);
        __syncthreads();                                     // B4
        #pragma unroll
        for (int t = 0; t < 6; ++t)
            #pragma unroll
            for (int j = 0; j < 4; ++j)
                ctxb[(16 * wv + 4 * lg + j) * LDC + 16 * t + lr] = (bf16_t)ctx[t][j];
    }
    __syncthreads();                                         // B5

    // ---- phase 4: proj + conditional LN + residual -> hs ----
    {
        const bf16_t* Wp = (const bf16_t*)(ws + WS_WP);
        bf16x8 wf[6][3];
        #pragma unroll
        for (int n = 0; n < 6; ++n)
            #pragma unroll
            for (int ks = 0; ks < 3; ++ks)
                wf[n][ks] = *(const bf16x8*)(Wp + (16 * n + lr) * LDC + 32 * ks + 8 * lg);
        bf16x8 af[3];
        #pragma unroll
        for (int ks = 0; ks < 3; ++ks) af[ks] = *(const bf16x8*)(ctxb + (16 * wv + lr) * LDC + 32 * ks + 8 * lg);
        f32x4 acc[6];
        #pragma unroll
        for (int n = 0; n < 6; ++n) {
            f32x4 a = {0.f,0.f,0.f,0.f};
            #pragma unroll
            for (int ks = 0; ks < 3; ++ks) a = mfma16(af[ks], wf[n][ks], a);
            float bp = pb[16 * n + lr];
            #pragma unroll
            for (int j = 0; j < 4; ++j) a[j] += bp;
            acc[n] = a;
        }
        float tb = tv[bat];
        float wco[6], bco[6];
        #pragma unroll
        for (int t = 0; t < 6; ++t) {
            int col = 16 * t + lr;
            wco[t] = fmaf(tb, lnww[col], lnwb[col]);
            bco[t] = fmaf(tb, lnbw[col], lnbb[col]);
        }
        #pragma unroll
        for (int j = 0; j < 4; ++j) {
            float smn = 0.f, sq = 0.f;
            #pragma unroll
            for (int t = 0; t < 6; ++t) { float v = acc[t][j]; smn += v; sq = fmaf(v, v, sq); }
            smn += __shfl_xor(smn, 1); smn += __shfl_xor(smn, 2); smn += __shfl_xor(smn, 4); smn += __shfl_xor(smn, 8);
            sq  += __shfl_xor(sq, 1);  sq  += __shfl_xor(sq, 2);  sq  += __shfl_xor(sq, 4);  sq  += __shfl_xor(sq, 8);
            float mean = smn * (1.f / 96.f);
            float var  = sq * (1.f / 96.f) - mean * mean;
            float rstd = rsqrtf(var + 1e-5f);
            int trow = 16 * wv + 4 * lg + j;
            int gr = ((hw << 3) + (trow >> 3) + 4) & 255;
            int gc = ((wwi << 3) + (trow & 7) + 4) & 255;
            size_t gbase = (((size_t)bat << 16) + (gr << 8) + gc) * 96;
            float hid[6];
            #pragma unroll
            for (int t = 0; t < 6; ++t) hid[t] = hidden[gbase + 16 * t + lr];
            #pragma unroll
            for (int t = 0; t < 6; ++t) {
                float xn = (acc[t][j] - mean) * rstd;
                hs[gbase + 16 * t + lr] = hid[t] + fmaf(wco[t], xn, bco[t]);
            }
        }
    }
}

// ---------------- Kernel B: MLP + conditional LN + residual (in-place on d_out) ----------------
// Weights fully LDS-resident (155.6 KB), 1 block/CU, 8 barrier-free waves x 4 tiles (2 at a time).
// fc1 swapped (D[mid][tok]); fc1->fc2 relayout via in-register lane exchange (no gbuf).
__global__ __launch_bounds__(512, 2) void kB_mlp(
    const float* __restrict__ tv, const float* __restrict__ fc1b,
    const float* __restrict__ fc2b,
    const float* __restrict__ lnww, const float* __restrict__ lnwb,
    const float* __restrict__ lnbw, const float* __restrict__ lnbb,
    const char* __restrict__ ws, float* __restrict__ io)
{
    __shared__ __align__(16) char smem[155648];
    const int tid = threadIdx.x;
    const int wv = tid >> 6, lane = tid & 63;
    const int lg = (lane >> 4) & 3, lr = lane & 15;

    // stage fc1+fc2 (155,136 B + pad) linearly into LDS
    {
        const float4* src = (const float4*)(ws + WS_FC1);
        float4* dst = (float4*)smem;
        #pragma unroll
        for (int r = 0; r < 19; ++r) {
            int idx = tid + 512 * r;              // *16B
            dst[idx] = src[idx];
        }
    }
    __syncthreads();                              // the ONLY barrier

    const bf16_t* w1 = (const bf16_t*)smem;             // [384][104]
    const bf16_t* w2 = (const bf16_t*)(smem + 79872);   // [96][392]

    #pragma unroll 1
    for (int pass = 0; pass < 2; ++pass) {
        const int tA = blockIdx.x * 32 + wv * 4 + pass * 2;   // tiles tA, tA+1 (16 tokens each)

        bf16x8 hf[2][3];
        float tb[2];
        #pragma unroll
        for (int p = 0; p < 2; ++p) {
            const int t0 = (tA + p) * 16;
            tb[p] = tv[(tA + p) >> 12];
            const float* hb = io + (size_t)(t0 + lr) * 96;
            #pragma unroll
            for (int ks = 0; ks < 3; ++ks) {
                float4 u0 = *(const float4*)(hb + 32 * ks + 8 * lg);
                float4 u1 = *(const float4*)(hb + 32 * ks + 8 * lg + 4);
                bf16x8 f;
                f[0] = (bf16_t)u0.x; f[1] = (bf16_t)u0.y; f[2] = (bf16_t)u0.z; f[3] = (bf16_t)u0.w;
                f[4] = (bf16_t)u1.x; f[5] = (bf16_t)u1.y; f[6] = (bf16_t)u1.z; f[7] = (bf16_t)u1.w;
                hf[p][ks] = f;
            }
        }

        f32x4 mlp[2][6];
        #pragma unroll
        for (int p = 0; p < 2; ++p)
            #pragma unroll
            for (int t = 0; t < 6; ++t) { f32x4 z = {0.f,0.f,0.f,0.f}; mlp[p][t] = z; }

        #pragma unroll
        for (int ch = 0; ch < 4; ++ch) {
            // fc1 (swapped): acc[p][nt] = D[mid=16nt+4lg+j (+96ch)][tok=lr]
            f32x4 acc[2][6];
            #pragma unroll
            for (int half = 0; half < 2; ++half) {
                bf16x8 a1[3][3];
                #pragma unroll
                for (int n2 = 0; n2 < 3; ++n2)
                    #pragma unroll
                    for (int ks = 0; ks < 3; ++ks)
                        a1[n2][ks] = *(const bf16x8*)(w1 + (96 * ch + 16 * (3 * half + n2) + lr) * LDC + 32 * ks + 8 * lg);
                #pragma unroll
                for (int p = 0; p < 2; ++p)
                    #pragma unroll
                    for (int n2 = 0; n2 < 3; ++n2) {
                        f32x4 a = {0.f,0.f,0.f,0.f};
                        #pragma unroll
                        for (int ks = 0; ks < 3; ++ks) a = mfma16(a1[n2][ks], hf[p][ks], a);
                        acc[p][3 * half + n2] = a;
                    }
            }
            // bias + gelu + pack to bf16 pairs
            uint32_t P0[2][6], P1[2][6];
            #pragma unroll
            for (int nt = 0; nt < 6; ++nt) {
                float4 b4 = *(const float4*)(fc1b + 96 * ch + 16 * nt + 4 * lg);
                #pragma unroll
                for (int p = 0; p < 2; ++p) {
                    float g_[4];
                    #pragma unroll
                    for (int j = 0; j < 4; ++j) {
                        float x = acc[p][nt][j] + ((const float*)&b4)[j];
                        float u = 0.7978845608f * fmaf(0.044715f * x, x * x, x);
                        float t = __expf(2.f * u);
                        g_[j] = x - x * __builtin_amdgcn_rcpf(t + 1.f);
                    }
                    P0[p][nt] = pk2(g_[0], g_[1]);
                    P1[p][nt] = pk2(g_[2], g_[3]);
                }
            }
            // fc2 over 3 k-steps: build g-frag (rows=tok, k=mid) by lane exchange
            const int s01 = lr + 32 * (lg & 1);
            const int s23 = s01 + 16;
            const bool hi = lg >= 2;
            #pragma unroll
            for (int kk = 0; kk < 3; ++kk) {
                int kkg = 3 * ch + kk;
                bf16x8 a2[6];
                #pragma unroll
                for (int ot = 0; ot < 6; ++ot)
                    a2[ot] = *(const bf16x8*)(w2 + (16 * ot + lr) * LDG + 32 * kkg + 8 * lg);
                #pragma unroll
                for (int p = 0; p < 2; ++p) {
                    uint32_t A0 = __shfl((int)P0[p][2*kk],   s01);
                    uint32_t A1 = __shfl((int)P1[p][2*kk],   s01);
                    uint32_t A2 = __shfl((int)P0[p][2*kk],   s23);
                    uint32_t A3 = __shfl((int)P1[p][2*kk],   s23);
                    uint32_t B0 = __shfl((int)P0[p][2*kk+1], s01);
                    uint32_t B1 = __shfl((int)P1[p][2*kk+1], s01);
                    uint32_t B2 = __shfl((int)P0[p][2*kk+1], s23);
                    uint32_t B3 = __shfl((int)P1[p][2*kk+1], s23);
                    union { uint32_t w[4]; bf16x8 v; } gg;
                    gg.w[0] = hi ? B0 : A0;
                    gg.w[1] = hi ? B1 : A1;
                    gg.w[2] = hi ? B2 : A2;
                    gg.w[3] = hi ? B3 : A3;
                    #pragma unroll
                    for (int ot = 0; ot < 6; ++ot)
                        mlp[p][ot] = mfma16(a2[ot], gg.v, mlp[p][ot]);
                }
            }
        }

        // epilogue per tile: bias, conditional LN over channels of token lr, residual, store
        #pragma unroll
        for (int p = 0; p < 2; ++p) {
            const int t0 = (tA + p) * 16;
            #pragma unroll
            for (int ot = 0; ot < 6; ++ot) {
                float4 b2 = *(const float4*)(fc2b + 16 * ot + 4 * lg);
                #pragma unroll
                for (int j = 0; j < 4; ++j) mlp[p][ot][j] += ((const float*)&b2)[j];
            }
            float smn = 0.f, sq = 0.f;
            #pragma unroll
            for (int ot = 0; ot < 6; ++ot)
                #pragma unroll
                for (int j = 0; j < 4; ++j) { float v = mlp[p][ot][j]; smn += v; sq = fmaf(v, v, sq); }
            smn += __shfl_xor(smn, 16); smn += __shfl_xor(smn, 32);
            sq  += __shfl_xor(sq, 16);  sq  += __shfl_xor(sq, 32);
            float mean = smn * (1.f / 96.f);
            float var  = sq * (1.f / 96.f) - mean * mean;
            float rstd = rsqrtf(var + 1e-5f);

            float* rowp = io + (size_t)(t0 + lr) * 96;
            #pragma unroll
            for (int ot = 0; ot < 6; ++ot) {
                float4 ww_ = *(const float4*)(lnww + 16 * ot + 4 * lg);
                float4 wb_ = *(const float4*)(lnwb + 16 * ot + 4 * lg);
                float4 bw_ = *(const float4*)(lnbw + 16 * ot + 4 * lg);
                float4 bb_ = *(const float4*)(lnbb + 16 * ot + 4 * lg);
                float4 hid = *(const float4*)(rowp + 16 * ot + 4 * lg);
                float4 o;
                #pragma unroll
                for (int j = 0; j < 4; ++j) {
                    float w = fmaf(tb[p], ((const float*)&ww_)[j], ((const float*)&wb_)[j]);
                    float b = fmaf(tb[p], ((const float*)&bw_)[j], ((const float*)&bb_)[j]);
                    float xn = (mlp[p][ot][j] - mean) * rstd;
                    ((float*)&o)[j] = ((const float*)&hid)[j] + fmaf(w, xn, b);
                }
                *(float4*)(rowp + 16 * ot + 4 * lg) = o;
            }
        }
    }
}

extern "C" void kernel_launch(void* const* d_in, const int* in_sizes, int n_in,
                              void* d_out, int out_size, void* d_ws, size_t ws_size,
                              hipStream_t stream)
{
    const float* hidden = (const float*)d_in[0];
    const float* tv     = (const float*)d_in[1];
    const float* q_w    = (const float*)d_in[2];
    const float* q_b    = (const float*)d_in[3];
    const float* k_w    = (const float*)d_in[4];
    const float* v_w    = (const float*)d_in[5];
    const float* v_b    = (const float*)d_in[6];
    const float* p_w    = (const float*)d_in[7];
    const float* p_b    = (const float*)d_in[8];
    const float* lsc    = (const float*)d_in[9];
    const float* cw1    = (const float*)d_in[10];
    const float* cb1    = (const float*)d_in[11];
    const float* cw2    = (const float*)d_in[12];
    const float* lnb_ww = (const float*)d_in[13];
    const float* lnb_wb = (const float*)d_in[14];
    const float* lnb_bw = (const float*)d_in[15];
    const float* lnb_bb = (const float*)d_in[16];
    const float* lna_ww = (const float*)d_in[17];
    const float* lna_wb = (const float*)d_in[18];
    const float* lna_bw = (const float*)d_in[19];
    const float* lna_bb = (const float*)d_in[20];
    const float* fc1_w  = (const float*)d_in[21];
    const float* fc1_b  = (const float*)d_in[22];
    const float* fc2_w  = (const float*)d_in[23];
    const float* fc2_b  = (const float*)d_in[24];
    char* ws = (char*)d_ws;
    float* out = (float*)d_out;

    k0a_cpb<<<dim3(57), dim3(256), 0, stream>>>(cw1, cb1, cw2, ws);
    k0w_prep<<<dim3(78), dim3(512), 0, stream>>>(q_w, k_w, v_w, p_w, fc1_w, fc2_w, ws);
    kA_attn<<<dim3(2048), dim3(256), 0, stream>>>(hidden, tv, q_b, v_b, p_b, lsc,
                                                  lnb_ww, lnb_wb, lnb_bw, lnb_bb, ws, out);
    kB_mlp<<<dim3(256), dim3(512), 0, stream>>>(tv, fc1_b, fc2_b,
                                                lna_ww, lna_wb, lna_bw, lna_bb, ws, out);
}

// Round 6
// 459.257 us; speedup vs baseline: 1.0208x; 1.0208x over previous
//
#include <hip/hip_runtime.h>
#include <hip/hip_bf16.h>

typedef __bf16 bf16_t;
typedef bf16_t bf16x8 __attribute__((ext_vector_type(8)));
typedef bf16_t bf16x4 __attribute__((ext_vector_type(4)));
typedef float  f32x4  __attribute__((ext_vector_type(4)));

#define LDC 104   // stride (bf16 elems) for 96-wide tiles
#define LDT 72    // stride for vT token dim
#define LDP 70    // stride for P token dim
#define LDG 394   // stride for fc2 weights [96][394] (pad: <=2-way LDS bank conflicts)

// ws layout (bytes)
#define WS_WQ    0
#define WS_WK    19968
#define WS_WV    39936
#define WS_WP    59904
#define WS_FC1   79872      // [384][104] bf16
#define WS_FC2   159744     // [96][394] bf16 (contiguous after FC1; 75,648 B)
#define WS_BIAS  235520     // [3][64 row][16 lr][4 f] f32 : 16*sigmoid(cpb bias), f4-transposed
#define WS_TBL   284672     // [225][3] f32 raw cpb table

__device__ __forceinline__ f32x4 mfma16(bf16x8 a, bf16x8 b, f32x4 c) {
    return __builtin_amdgcn_mfma_f32_16x16x32_bf16(a, b, c, 0, 0, 0);
}

__device__ __forceinline__ float cpbf(int v) {   // v in -7..7
    float x = (float)v * (8.0f / 7.0f);
    float l = log2f(fabsf(x) + 1.0f) * (1.0f / 3.0f);
    return x < 0.f ? -l : l;
}

__device__ __forceinline__ int regcnt(int t, int hw, int ww) {
    int r = t >> 3, c = t & 7;
    int rr = (hw == 31) ? (r < 4 ? 1 : 2) : 0;
    int cc = (ww == 31) ? (c < 4 ? 1 : 2) : 0;
    return rr * 3 + cc;
}

__device__ __forceinline__ uint32_t pk2(float lo, float hi) {
    union { bf16_t h[2]; uint32_t u; } z;
    z.h[0] = (bf16_t)lo; z.h[1] = (bf16_t)hi;
    return z.u;
}

// ---------------- k0a: CPB table — one WAVE per entry ----------------
__global__ __launch_bounds__(256) void k0a_cpb(
    const float* __restrict__ cw1, const float* __restrict__ cb1,
    const float* __restrict__ cw2, char* __restrict__ ws)
{
    const int wv = threadIdx.x >> 6, lane = threadIdx.x & 63;
    const int e = blockIdx.x * 4 + wv;
    if (e >= 225) return;
    int ia = e / 15, ib = e % 15;
    float c0 = cpbf(ia - 7), c1 = cpbf(ib - 7);
    float a0 = 0.f, a1 = 0.f, a2 = 0.f;
    #pragma unroll
    for (int c = 0; c < 8; ++c) {
        int j = c * 64 + lane;
        float h = fmaf(c0, cw1[j], fmaf(c1, cw1[512 + j], cb1[j]));
        h = fmaxf(h, 0.f);
        a0 = fmaf(h, cw2[j * 3 + 0], a0);
        a1 = fmaf(h, cw2[j * 3 + 1], a1);
        a2 = fmaf(h, cw2[j * 3 + 2], a2);
    }
    #pragma unroll
    for (int m = 1; m < 64; m <<= 1) {
        a0 += __shfl_xor(a0, m);
        a1 += __shfl_xor(a1, m);
        a2 += __shfl_xor(a2, m);
    }
    if (lane == 0) {
        float* tbl = (float*)(ws + WS_TBL);
        tbl[e * 3 + 0] = a0; tbl[e * 3 + 1] = a1; tbl[e * 3 + 2] = a2;
    }
}

// ---------------- k0w: weight repack (blocks 0..53) + bias expand (blocks 54..77) ----------------
__global__ __launch_bounds__(512) void k0w_prep(
    const float* __restrict__ qw, const float* __restrict__ kw,
    const float* __restrict__ vw, const float* __restrict__ pw,
    const float* __restrict__ fc1w, const float* __restrict__ fc2w,
    char* __restrict__ ws)
{
    int tid = threadIdx.x;
    if (blockIdx.x < 54) {
        int rid = blockIdx.x * 512 + tid;            // 0..27647, float4-coalesced reads
        if (rid < 9216) {                            // q,k,v,proj: [96 in][96 out] -> [out][in]
            int which = rid / 2304, r = rid % 2304;
            int i = r / 24, o4 = r % 24;
            const float* src = which == 0 ? qw : which == 1 ? kw : which == 2 ? vw : pw;
            float4 u = *(const float4*)(src + i * 96 + 4 * o4);
            bf16_t* dst = (bf16_t*)(ws + WS_WQ + which * 19968);
            dst[(4 * o4 + 0) * LDC + i] = (bf16_t)u.x;
            dst[(4 * o4 + 1) * LDC + i] = (bf16_t)u.y;
            dst[(4 * o4 + 2) * LDC + i] = (bf16_t)u.z;
            dst[(4 * o4 + 3) * LDC + i] = (bf16_t)u.w;
        } else if (rid < 18432) {                    // fc1: [96][384] -> [384][104]
            int r = rid - 9216;
            int i = r / 96, m4 = r % 96;
            float4 u = *(const float4*)(fc1w + i * 384 + 4 * m4);
            bf16_t* dst = (bf16_t*)(ws + WS_FC1);
            dst[(4 * m4 + 0) * LDC + i] = (bf16_t)u.x;
            dst[(4 * m4 + 1) * LDC + i] = (bf16_t)u.y;
            dst[(4 * m4 + 2) * LDC + i] = (bf16_t)u.z;
            dst[(4 * m4 + 3) * LDC + i] = (bf16_t)u.w;
        } else {                                     // fc2: [384][96] -> [96][394]
            int r = rid - 18432;
            int g = r / 24, o4 = r % 24;
            float4 u = *(const float4*)(fc2w + g * 96 + 4 * o4);
            bf16_t* dst = (bf16_t*)(ws + WS_FC2);
            dst[(4 * o4 + 0) * LDG + g] = (bf16_t)u.x;
            dst[(4 * o4 + 1) * LDG + g] = (bf16_t)u.y;
            dst[(4 * o4 + 2) * LDG + g] = (bf16_t)u.z;
            dst[(4 * o4 + 3) * LDG + g] = (bf16_t)u.w;
        }
    } else {
        int e = (blockIdx.x - 54) * 512 + tid;       // 0..12287 (h, row n, col m)
        if (e < 12288) {
            const float* tbl = (const float*)(ws + WS_TBL);
            float* bias = (float*)(ws + WS_BIAS);
            int h = e >> 12, nm = e & 4095, n = nm >> 6, m = nm & 63;
            int dr = (n >> 3) - (m >> 3) + 7, dc = (n & 7) - (m & 7) + 7;
            float t = tbl[(dr * 15 + dc) * 3 + h];
            // f4-transposed layout: [h][row][m&15][m>>4]
            bias[(h << 12) | (n << 6) | ((m & 15) << 2) | (m >> 4)] = 16.f / (1.f + __expf(-t));
        }
    }
}

// ---------------- Kernel A: fused window attention -> hs (into d_out) ----------------
__global__ __launch_bounds__(256, 3) void kA_attn(
    const float* __restrict__ hidden, const float* __restrict__ tv,
    const float* __restrict__ qb, const float* __restrict__ vb,
    const float* __restrict__ pb, const float* __restrict__ lsc,
    const float* __restrict__ lnww, const float* __restrict__ lnwb,
    const float* __restrict__ lnbw, const float* __restrict__ lnbb,
    const char* __restrict__ ws, float* __restrict__ hs)
{
    __shared__ __align__(16) char sm[40704];
    bf16_t* vT   = (bf16_t*)(sm + 0);         // [96][72]   = 13824
    bf16_t* qn   = (bf16_t*)(sm + 13824);     // [64][104]  = 13312
    bf16_t* kn   = (bf16_t*)(sm + 27136);     // [64][104]  = 13312
    bf16_t* P    = (bf16_t*)(sm + 13824);     // [3][64][70], overlays qn+kn (after B2)
    bf16_t* ctxb = (bf16_t*)(sm + 0);         // [64][104], overlays vT (after B4)

    const int tid = threadIdx.x;
    const int wv = tid >> 6, lane = tid & 63, lg = lane >> 4, lr = lane & 15;
    const int wid = blockIdx.x;
    const int bat = wid >> 10, wim = wid & 1023, hw = wim >> 5, wwi = wim & 31;

    // ---- phase 1: QKV ----
    {
        bf16x8 af[3];
        {
            int tok = 16 * wv + lr;
            int gr = ((hw << 3) + (tok >> 3) + 4) & 255;
            int gc = ((wwi << 3) + (tok & 7) + 4) & 255;
            const float* xb = hidden + (((size_t)bat << 16) + (gr << 8) + gc) * 96;
            #pragma unroll
            for (int ks = 0; ks < 3; ++ks) {
                float4 u0 = *(const float4*)(xb + 32 * ks + 8 * lg);
                float4 u1 = *(const float4*)(xb + 32 * ks + 8 * lg + 4);
                bf16x8 f;
                f[0] = (bf16_t)u0.x; f[1] = (bf16_t)u0.y; f[2] = (bf16_t)u0.z; f[3] = (bf16_t)u0.w;
                f[4] = (bf16_t)u1.x; f[5] = (bf16_t)u1.y; f[6] = (bf16_t)u1.z; f[7] = (bf16_t)u1.w;
                af[ks] = f;
            }
        }
        const bf16_t* Wq = (const bf16_t*)(ws + WS_WQ);
        const bf16_t* Wk = (const bf16_t*)(ws + WS_WK);
        const bf16_t* Wv = (const bf16_t*)(ws + WS_WV);

        {   // Q
            bf16x8 wf[6][3];
            #pragma unroll
            for (int n = 0; n < 6; ++n)
                #pragma unroll
                for (int ks = 0; ks < 3; ++ks)
                    wf[n][ks] = *(const bf16x8*)(Wq + (16 * n + lr) * LDC + 32 * ks + 8 * lg);
            f32x4 acc[6];
            #pragma unroll
            for (int n = 0; n < 6; ++n) {
                f32x4 a = {0.f,0.f,0.f,0.f};
                #pragma unroll
                for (int ks = 0; ks < 3; ++ks) a = mfma16(af[ks], wf[n][ks], a);
                float bq = qb[16 * n + lr];
                #pragma unroll
                for (int j = 0; j < 4; ++j) a[j] += bq;
                acc[n] = a;
            }
            #pragma unroll
            for (int h = 0; h < 3; ++h)
                #pragma unroll
                for (int j = 0; j < 4; ++j) {
                    float s = acc[2*h][j] * acc[2*h][j] + acc[2*h+1][j] * acc[2*h+1][j];
                    s += __shfl_xor(s, 1); s += __shfl_xor(s, 2); s += __shfl_xor(s, 4); s += __shfl_xor(s, 8);
                    float inv = 1.f / fmaxf(sqrtf(s), 1e-12f);
                    int row = 16 * wv + 4 * lg + j;
                    qn[row * LDC + 32 * h + lr]      = (bf16_t)(acc[2*h][j] * inv);
                    qn[row * LDC + 32 * h + 16 + lr] = (bf16_t)(acc[2*h+1][j] * inv);
                }
        }
        {   // K
            bf16x8 wf[6][3];
            #pragma unroll
            for (int n = 0; n < 6; ++n)
                #pragma unroll
                for (int ks = 0; ks < 3; ++ks)
                    wf[n][ks] = *(const bf16x8*)(Wk + (16 * n + lr) * LDC + 32 * ks + 8 * lg);
            f32x4 acc[6];
            #pragma unroll
            for (int n = 0; n < 6; ++n) {
                f32x4 a = {0.f,0.f,0.f,0.f};
                #pragma unroll
                for (int ks = 0; ks < 3; ++ks) a = mfma16(af[ks], wf[n][ks], a);
                acc[n] = a;
            }
            #pragma unroll
            for (int h = 0; h < 3; ++h)
                #pragma unroll
                for (int j = 0; j < 4; ++j) {
                    float s = acc[2*h][j] * acc[2*h][j] + acc[2*h+1][j] * acc[2*h+1][j];
                    s += __shfl_xor(s, 1); s += __shfl_xor(s, 2); s += __shfl_xor(s, 4); s += __shfl_xor(s, 8);
                    float inv = 1.f / fmaxf(sqrtf(s), 1e-12f);
                    int row = 16 * wv + 4 * lg + j;
                    kn[row * LDC + 32 * h + lr]      = (bf16_t)(acc[2*h][j] * inv);
                    kn[row * LDC + 32 * h + 16 + lr] = (bf16_t)(acc[2*h+1][j] * inv);
                }
        }
        {   // V (store transposed)
            bf16x8 wf[6][3];
            #pragma unroll
            for (int n = 0; n < 6; ++n)
                #pragma unroll
                for (int ks = 0; ks < 3; ++ks)
                    wf[n][ks] = *(const bf16x8*)(Wv + (16 * n + lr) * LDC + 32 * ks + 8 * lg);
            #pragma unroll
            for (int n = 0; n < 6; ++n) {
                f32x4 a = {0.f,0.f,0.f,0.f};
                #pragma unroll
                for (int ks = 0; ks < 3; ++ks) a = mfma16(af[ks], wf[n][ks], a);
                float bv_ = vb[16 * n + lr];
                bf16x4 pk;
                #pragma unroll
                for (int j = 0; j < 4; ++j) pk[j] = (bf16_t)(a[j] + bv_);
                *(bf16x4*)(vT + (16 * n + lr) * LDT + 16 * wv + 4 * lg) = pk;
            }
        }
    }
    __syncthreads();                                         // B1

    // ---- phase 2: S = qn@kn^T (+bias+mask), softmax, write P ----
    {
        float br[3][4][4];
        const float* biasT = (const float*)(ws + WS_BIAS);
        #pragma unroll
        for (int h = 0; h < 3; ++h)
            #pragma unroll
            for (int j = 0; j < 4; ++j) {
                float4 u = *(const float4*)(biasT + (h << 12) + ((16 * wv + 4 * lg + j) << 6) + (lr << 2));
                br[h][0][j] = u.x; br[h][1][j] = u.y; br[h][2][j] = u.z; br[h][3][j] = u.w;
            }

        f32x4 s[3][4];
        #pragma unroll
        for (int h = 0; h < 3; ++h) {
            bf16x8 aq = *(const bf16x8*)(qn + (16 * wv + lr) * LDC + 32 * h + 8 * lg);
            bf16x8 bk[4];
            #pragma unroll
            for (int f = 0; f < 4; ++f)
                bk[f] = *(const bf16x8*)(kn + (16 * f + lr) * LDC + 32 * h + 8 * lg);
            #pragma unroll
            for (int f = 0; f < 4; ++f) {
                f32x4 z = {0.f,0.f,0.f,0.f};
                s[h][f] = mfma16(aq, bk[f], z);
            }
        }
        __syncthreads();                                     // B2

        float ls[3];
        #pragma unroll
        for (int h = 0; h < 3; ++h) ls[h] = __expf(fminf(lsc[h], 4.6051702f));
        int cntm[4], cnti[4];
        #pragma unroll
        for (int f = 0; f < 4; ++f) cntm[f] = regcnt(16 * f + lr, hw, wwi);
        #pragma unroll
        for (int j = 0; j < 4; ++j) cnti[j] = regcnt(16 * wv + 4 * lg + j, hw, wwi);
        #pragma unroll
        for (int h = 0; h < 3; ++h) {
            #pragma unroll
            for (int f = 0; f < 4; ++f)
                #pragma unroll
                for (int j = 0; j < 4; ++j) {
                    float mk = (cnti[j] != cntm[f]) ? -100.f : 0.f;
                    s[h][f][j] = fmaf(s[h][f][j], ls[h], br[h][f][j] + mk);
                }
            #pragma unroll
            for (int j = 0; j < 4; ++j) {
                float mx = fmaxf(fmaxf(s[h][0][j], s[h][1][j]), fmaxf(s[h][2][j], s[h][3][j]));
                mx = fmaxf(mx, __shfl_xor(mx, 1)); mx = fmaxf(mx, __shfl_xor(mx, 2));
                mx = fmaxf(mx, __shfl_xor(mx, 4)); mx = fmaxf(mx, __shfl_xor(mx, 8));
                float sum = 0.f;
                #pragma unroll
                for (int f = 0; f < 4; ++f) { float e = __expf(s[h][f][j] - mx); s[h][f][j] = e; sum += e; }
                sum += __shfl_xor(sum, 1); sum += __shfl_xor(sum, 2); sum += __shfl_xor(sum, 4); sum += __shfl_xor(sum, 8);
                float inv = 1.f / sum;
                int row = 16 * wv + 4 * lg + j;
                #pragma unroll
                for (int f = 0; f < 4; ++f)
                    P[h * 64 * LDP + row * LDP + 16 * f + lr] = (bf16_t)(s[h][f][j] * inv);
            }
        }
    }
    __syncthreads();                                         // B3

    // ---- phase 3: ctx = P@V ----
    {
        f32x4 ctx[6];
        #pragma unroll
        for (int t = 0; t < 6; ++t) { f32x4 z = {0.f,0.f,0.f,0.f}; ctx[t] = z; }
        bf16x8 ap[3][2], bv2[3][2][2];
        #pragma unroll
        for (int h = 0; h < 3; ++h)
            #pragma unroll
            for (int ks = 0; ks < 2; ++ks) {
                ap[h][ks] = *(const bf16x8*)(P + h * 64 * LDP + (16 * wv + lr) * LDP + 32 * ks + 8 * lg);
                #pragma unroll
                for (int dt = 0; dt < 2; ++dt)
                    bv2[h][dt][ks] = *(const bf16x8*)(vT + (32 * h + 16 * dt + lr) * LDT + 32 * ks + 8 * lg);
            }
        #pragma unroll
        for (int h = 0; h < 3; ++h)
            #pragma unroll
            for (int ks = 0; ks < 2; ++ks)
                #pragma unroll
                for (int dt = 0; dt < 2; ++dt)
                    ctx[2 * h + dt] = mfma16(ap[h][ks], bv2[h][dt][ks], ctx[2 * h + dt]);
        __syncthreads();                                     // B4
        #pragma unroll
        for (int t = 0; t < 6; ++t)
            #pragma unroll
            for (int j = 0; j < 4; ++j)
                ctxb[(16 * wv + 4 * lg + j) * LDC + 16 * t + lr] = (bf16_t)ctx[t][j];
    }
    __syncthreads();                                         // B5

    // ---- phase 4: proj + conditional LN + residual -> hs ----
    {
        const bf16_t* Wp = (const bf16_t*)(ws + WS_WP);
        bf16x8 wf[6][3];
        #pragma unroll
        for (int n = 0; n < 6; ++n)
            #pragma unroll
            for (int ks = 0; ks < 3; ++ks)
                wf[n][ks] = *(const bf16x8*)(Wp + (16 * n + lr) * LDC + 32 * ks + 8 * lg);
        bf16x8 af[3];
        #pragma unroll
        for (int ks = 0; ks < 3; ++ks) af[ks] = *(const bf16x8*)(ctxb + (16 * wv + lr) * LDC + 32 * ks + 8 * lg);
        f32x4 acc[6];
        #pragma unroll
        for (int n = 0; n < 6; ++n) {
            f32x4 a = {0.f,0.f,0.f,0.f};
            #pragma unroll
            for (int ks = 0; ks < 3; ++ks) a = mfma16(af[ks], wf[n][ks], a);
            float bp = pb[16 * n + lr];
            #pragma unroll
            for (int j = 0; j < 4; ++j) a[j] += bp;
            acc[n] = a;
        }
        float tb = tv[bat];
        float wco[6], bco[6];
        #pragma unroll
        for (int t = 0; t < 6; ++t) {
            int col = 16 * t + lr;
            wco[t] = fmaf(tb, lnww[col], lnwb[col]);
            bco[t] = fmaf(tb, lnbw[col], lnbb[col]);
        }
        #pragma unroll
        for (int j = 0; j < 4; ++j) {
            float smn = 0.f, sq = 0.f;
            #pragma unroll
            for (int t = 0; t < 6; ++t) { float v = acc[t][j]; smn += v; sq = fmaf(v, v, sq); }
            smn += __shfl_xor(smn, 1); smn += __shfl_xor(smn, 2); smn += __shfl_xor(smn, 4); smn += __shfl_xor(smn, 8);
            sq  += __shfl_xor(sq, 1);  sq  += __shfl_xor(sq, 2);  sq  += __shfl_xor(sq, 4);  sq  += __shfl_xor(sq, 8);
            float mean = smn * (1.f / 96.f);
            float var  = sq * (1.f / 96.f) - mean * mean;
            float rstd = rsqrtf(var + 1e-5f);
            int trow = 16 * wv + 4 * lg + j;
            int gr = ((hw << 3) + (trow >> 3) + 4) & 255;
            int gc = ((wwi << 3) + (trow & 7) + 4) & 255;
            size_t gbase = (((size_t)bat << 16) + (gr << 8) + gc) * 96;
            float hid[6];
            #pragma unroll
            for (int t = 0; t < 6; ++t) hid[t] = hidden[gbase + 16 * t + lr];
            #pragma unroll
            for (int t = 0; t < 6; ++t) {
                float xn = (acc[t][j] - mean) * rstd;
                hs[gbase + 16 * t + lr] = hid[t] + fmaf(wco[t], xn, bco[t]);
            }
        }
    }
}

// ---------------- Kernel B: MLP + conditional LN + residual (in-place on d_out) ----------------
// Weights fully LDS-resident (155.6 KB), 1 block/CU (launch_bounds(512,1) -> 256 VGPR budget,
// NO spills), 8 barrier-free waves x 2 passes x 2 tiles.
// fc1 swapped (D[mid][tok]); fc1->fc2 relayout via in-register lane exchange (no gbuf).
__global__ __launch_bounds__(512, 1) void kB_mlp(
    const float* __restrict__ tv, const float* __restrict__ fc1b,
    const float* __restrict__ fc2b,
    const float* __restrict__ lnww, const float* __restrict__ lnwb,
    const float* __restrict__ lnbw, const float* __restrict__ lnbb,
    const char* __restrict__ ws, float* __restrict__ io)
{
    __shared__ __align__(16) char smem[155648];
    const int tid = threadIdx.x;
    const int wv = tid >> 6, lane = tid & 63;
    const int lg = (lane >> 4) & 3, lr = lane & 15;

    // stage fc1+fc2 (155,520 B + pad) linearly into LDS
    {
        const float4* src = (const float4*)(ws + WS_FC1);
        float4* dst = (float4*)smem;
        #pragma unroll
        for (int r = 0; r < 19; ++r) {
            int idx = tid + 512 * r;              // *16B
            dst[idx] = src[idx];
        }
    }
    __syncthreads();                              // the ONLY barrier

    const bf16_t* w1 = (const bf16_t*)smem;             // [384][104]
    const bf16_t* w2 = (const bf16_t*)(smem + 79872);   // [96][394]

    #pragma unroll 1
    for (int pass = 0; pass < 2; ++pass) {
        const int tA = blockIdx.x * 32 + wv * 4 + pass * 2;   // tiles tA, tA+1 (16 tokens each)

        bf16x8 hf[2][3];
        float tb[2];
        #pragma unroll
        for (int p = 0; p < 2; ++p) {
            const int t0 = (tA + p) * 16;
            tb[p] = tv[(tA + p) >> 12];
            const float* hb = io + (size_t)(t0 + lr) * 96;
            #pragma unroll
            for (int ks = 0; ks < 3; ++ks) {
                float4 u0 = *(const float4*)(hb + 32 * ks + 8 * lg);
                float4 u1 = *(const float4*)(hb + 32 * ks + 8 * lg + 4);
                bf16x8 f;
                f[0] = (bf16_t)u0.x; f[1] = (bf16_t)u0.y; f[2] = (bf16_t)u0.z; f[3] = (bf16_t)u0.w;
                f[4] = (bf16_t)u1.x; f[5] = (bf16_t)u1.y; f[6] = (bf16_t)u1.z; f[7] = (bf16_t)u1.w;
                hf[p][ks] = f;
            }
        }

        f32x4 mlp[2][6];
        #pragma unroll
        for (int p = 0; p < 2; ++p)
            #pragma unroll
            for (int t = 0; t < 6; ++t) { f32x4 z = {0.f,0.f,0.f,0.f}; mlp[p][t] = z; }

        #pragma unroll
        for (int ch = 0; ch < 4; ++ch) {
            // fc1 (swapped): acc[p][nt] = D[mid=16nt+4lg+j (+96ch)][tok=lr]
            f32x4 acc[2][6];
            #pragma unroll
            for (int half = 0; half < 2; ++half) {
                bf16x8 a1[3][3];
                #pragma unroll
                for (int n2 = 0; n2 < 3; ++n2)
                    #pragma unroll
                    for (int ks = 0; ks < 3; ++ks)
                        a1[n2][ks] = *(const bf16x8*)(w1 + (96 * ch + 16 * (3 * half + n2) + lr) * LDC + 32 * ks + 8 * lg);
                #pragma unroll
                for (int p = 0; p < 2; ++p)
                    #pragma unroll
                    for (int n2 = 0; n2 < 3; ++n2) {
                        f32x4 a = {0.f,0.f,0.f,0.f};
                        #pragma unroll
                        for (int ks = 0; ks < 3; ++ks) a = mfma16(a1[n2][ks], hf[p][ks], a);
                        acc[p][3 * half + n2] = a;
                    }
            }
            // bias + gelu + pack to bf16 pairs
            uint32_t P0[2][6], P1[2][6];
            #pragma unroll
            for (int nt = 0; nt < 6; ++nt) {
                float4 b4 = *(const float4*)(fc1b + 96 * ch + 16 * nt + 4 * lg);
                #pragma unroll
                for (int p = 0; p < 2; ++p) {
                    float g_[4];
                    #pragma unroll
                    for (int j = 0; j < 4; ++j) {
                        float x = acc[p][nt][j] + ((const float*)&b4)[j];
                        float u = 0.7978845608f * fmaf(0.044715f * x, x * x, x);
                        float t = __expf(2.f * u);
                        g_[j] = x - x * __builtin_amdgcn_rcpf(t + 1.f);
                    }
                    P0[p][nt] = pk2(g_[0], g_[1]);
                    P1[p][nt] = pk2(g_[2], g_[3]);
                }
            }
            // fc2 over 3 k-steps: build g-frag (rows=tok, k=mid) by lane exchange
            const int s01 = lr + 32 * (lg & 1);
            const int s23 = s01 + 16;
            const bool hi = lg >= 2;
            #pragma unroll
            for (int kk = 0; kk < 3; ++kk) {
                int kkg = 3 * ch + kk;
                bf16x8 a2[6];
                #pragma unroll
                for (int ot = 0; ot < 6; ++ot)
                    a2[ot] = *(const bf16x8*)(w2 + (16 * ot + lr) * LDG + 32 * kkg + 8 * lg);
                #pragma unroll
                for (int p = 0; p < 2; ++p) {
                    uint32_t A0 = __shfl((int)P0[p][2*kk],   s01);
                    uint32_t A1 = __shfl((int)P1[p][2*kk],   s01);
                    uint32_t A2 = __shfl((int)P0[p][2*kk],   s23);
                    uint32_t A3 = __shfl((int)P1[p][2*kk],   s23);
                    uint32_t B0 = __shfl((int)P0[p][2*kk+1], s01);
                    uint32_t B1 = __shfl((int)P1[p][2*kk+1], s01);
                    uint32_t B2 = __shfl((int)P0[p][2*kk+1], s23);
                    uint32_t B3 = __shfl((int)P1[p][2*kk+1], s23);
                    union { uint32_t w[4]; bf16x8 v; } gg;
                    gg.w[0] = hi ? B0 : A0;
                    gg.w[1] = hi ? B1 : A1;
                    gg.w[2] = hi ? B2 : A2;
                    gg.w[3] = hi ? B3 : A3;
                    #pragma unroll
                    for (int ot = 0; ot < 6; ++ot)
                        mlp[p][ot] = mfma16(a2[ot], gg.v, mlp[p][ot]);
                }
            }
        }

        // epilogue per tile: bias, conditional LN over channels of token lr, residual, store
        #pragma unroll
        for (int p = 0; p < 2; ++p) {
            const int t0 = (tA + p) * 16;
            #pragma unroll
            for (int ot = 0; ot < 6; ++ot) {
                float4 b2 = *(const float4*)(fc2b + 16 * ot + 4 * lg);
                #pragma unroll
                for (int j = 0; j < 4; ++j) mlp[p][ot][j] += ((const float*)&b2)[j];
            }
            float smn = 0.f, sq = 0.f;
            #pragma unroll
            for (int ot = 0; ot < 6; ++ot)
                #pragma unroll
                for (int j = 0; j < 4; ++j) { float v = mlp[p][ot][j]; smn += v; sq = fmaf(v, v, sq); }
            smn += __shfl_xor(smn, 16); smn += __shfl_xor(smn, 32);
            sq  += __shfl_xor(sq, 16);  sq  += __shfl_xor(sq, 32);
            float mean = smn * (1.f / 96.f);
            float var  = sq * (1.f / 96.f) - mean * mean;
            float rstd = rsqrtf(var + 1e-5f);

            float* rowp = io + (size_t)(t0 + lr) * 96;
            #pragma unroll
            for (int ot = 0; ot < 6; ++ot) {
                float4 ww_ = *(const float4*)(lnww + 16 * ot + 4 * lg);
                float4 wb_ = *(const float4*)(lnwb + 16 * ot + 4 * lg);
                float4 bw_ = *(const float4*)(lnbw + 16 * ot + 4 * lg);
                float4 bb_ = *(const float4*)(lnbb + 16 * ot + 4 * lg);
                float4 hid = *(const float4*)(rowp + 16 * ot + 4 * lg);
                float4 o;
                #pragma unroll
                for (int j = 0; j < 4; ++j) {
                    float w = fmaf(tb[p], ((const float*)&ww_)[j], ((const float*)&wb_)[j]);
                    float b = fmaf(tb[p], ((const float*)&bw_)[j], ((const float*)&bb_)[j]);
                    float xn = (mlp[p][ot][j] - mean) * rstd;
                    ((float*)&o)[j] = ((const float*)&hid)[j] + fmaf(w, xn, b);
                }
                *(float4*)(rowp + 16 * ot + 4 * lg) = o;
            }
        }
    }
}

extern "C" void kernel_launch(void* const* d_in, const int* in_sizes, int n_in,
                              void* d_out, int out_size, void* d_ws, size_t ws_size,
                              hipStream_t stream)
{
    const float* hidden = (const float*)d_in[0];
    const float* tv     = (const float*)d_in[1];
    const float* q_w    = (const float*)d_in[2];
    const float* q_b    = (const float*)d_in[3];
    const float* k_w    = (const float*)d_in[4];
    const float* v_w    = (const float*)d_in[5];
    const float* v_b    = (const float*)d_in[6];
    const float* p_w    = (const float*)d_in[7];
    const float* p_b    = (const float*)d_in[8];
    const float* lsc    = (const float*)d_in[9];
    const float* cw1    = (const float*)d_in[10];
    const float* cb1    = (const float*)d_in[11];
    const float* cw2    = (const float*)d_in[12];
    const float* lnb_ww = (const float*)d_in[13];
    const float* lnb_wb = (const float*)d_in[14];
    const float* lnb_bw = (const float*)d_in[15];
    const float* lnb_bb = (const float*)d_in[16];
    const float* lna_ww = (const float*)d_in[17];
    const float* lna_wb = (const float*)d_in[18];
    const float* lna_bw = (const float*)d_in[19];
    const float* lna_bb = (const float*)d_in[20];
    const float* fc1_w  = (const float*)d_in[21];
    const float* fc1_b  = (const float*)d_in[22];
    const float* fc2_w  = (const float*)d_in[23];
    const float* fc2_b  = (const float*)d_in[24];
    char* ws = (char*)d_ws;
    float* out = (float*)d_out;

    k0a_cpb<<<dim3(57), dim3(256), 0, stream>>>(cw1, cb1, cw2, ws);
    k0w_prep<<<dim3(78), dim3(512), 0, stream>>>(q_w, k_w, v_w, p_w, fc1_w, fc2_w, ws);
    kA_attn<<<dim3(2048), dim3(256), 0, stream>>>(hidden, tv, q_b, v_b, p_b, lsc,
                                                  lnb_ww, lnb_wb, lnb_bw, lnb_bb, ws, out);
    kB_mlp<<<dim3(256), dim3(512), 0, stream>>>(tv, fc1_b, fc2_b,
                                                lna_ww, lna_wb, lna_bw, lna_bb, ws, out);
}

// Round 9
// 293.343 us; speedup vs baseline: 1.5982x; 1.5656x over previous
//
#include <hip/hip_runtime.h>
#include <hip/hip_bf16.h>

typedef __bf16 bf16_t;
typedef bf16_t bf16x8 __attribute__((ext_vector_type(8)));
typedef bf16_t bf16x4 __attribute__((ext_vector_type(4)));
typedef float  f32x4  __attribute__((ext_vector_type(4)));

#define LDC 104   // stride (bf16 elems) for 96-wide qkvp tiles + gbuf
#define LDW 100   // stride for fc1/fc2 weight tiles (16 lanes -> 16 distinct banks)
#define LDT 72    // stride for vT token dim (verified R6)
#define LDP 70    // stride for P token dim

// ws layout (bytes) — total footprint 285,324 B (< R6-verified 287,372)
#define WS_WQ    0
#define WS_WK    19968
#define WS_WV    39936
#define WS_WP    59904
#define WS_FC1   79872      // [384][100] bf16 = 76,800 B
#define WS_FC2   156672     // [4][96][100] bf16 = 76,800 B
#define WS_BIAS  233472     // [3][64 row][16 lr][4 f] f32 = 49,152 B
#define WS_TBL   282624     // [225][3] f32 raw cpb table = 2,700 B

__device__ __forceinline__ f32x4 mfma16(bf16x8 a, bf16x8 b, f32x4 c) {
    return __builtin_amdgcn_mfma_f32_16x16x32_bf16(a, b, c, 0, 0, 0);
}

__device__ __forceinline__ float cpbf(int v) {   // v in -7..7
    float x = (float)v * (8.0f / 7.0f);
    float l = log2f(fabsf(x) + 1.0f) * (1.0f / 3.0f);
    return x < 0.f ? -l : l;
}

__device__ __forceinline__ int regcnt(int t, int hw, int ww) {
    int r = t >> 3, c = t & 7;
    int rr = (hw == 31) ? (r < 4 ? 1 : 2) : 0;
    int cc = (ww == 31) ? (c < 4 ? 1 : 2) : 0;
    return rr * 3 + cc;
}

// ---------------- k0a: CPB table — one WAVE per entry ----------------
__global__ __launch_bounds__(256) void k0a_cpb(
    const float* __restrict__ cw1, const float* __restrict__ cb1,
    const float* __restrict__ cw2, char* __restrict__ ws)
{
    const int wv = threadIdx.x >> 6, lane = threadIdx.x & 63;
    const int e = blockIdx.x * 4 + wv;
    if (e >= 225) return;
    int ia = e / 15, ib = e % 15;
    float c0 = cpbf(ia - 7), c1 = cpbf(ib - 7);
    float a0 = 0.f, a1 = 0.f, a2 = 0.f;
    #pragma unroll
    for (int c = 0; c < 8; ++c) {
        int j = c * 64 + lane;
        float h = fmaf(c0, cw1[j], fmaf(c1, cw1[512 + j], cb1[j]));
        h = fmaxf(h, 0.f);
        a0 = fmaf(h, cw2[j * 3 + 0], a0);
        a1 = fmaf(h, cw2[j * 3 + 1], a1);
        a2 = fmaf(h, cw2[j * 3 + 2], a2);
    }
    #pragma unroll
    for (int m = 1; m < 64; m <<= 1) {
        a0 += __shfl_xor(a0, m);
        a1 += __shfl_xor(a1, m);
        a2 += __shfl_xor(a2, m);
    }
    if (lane == 0) {
        float* tbl = (float*)(ws + WS_TBL);
        tbl[e * 3 + 0] = a0; tbl[e * 3 + 1] = a1; tbl[e * 3 + 2] = a2;
    }
}

// ---------------- k0w: weight repack (blocks 0..53) + bias expand (blocks 54..77) ----------------
__global__ __launch_bounds__(512) void k0w_prep(
    const float* __restrict__ qw, const float* __restrict__ kw,
    const float* __restrict__ vw, const float* __restrict__ pw,
    const float* __restrict__ fc1w, const float* __restrict__ fc2w,
    char* __restrict__ ws)
{
    int tid = threadIdx.x;
    if (blockIdx.x < 54) {
        int rid = blockIdx.x * 512 + tid;            // 0..27647, float4-coalesced reads
        if (rid < 9216) {                            // q,k,v,proj: [96 in][96 out] -> [out][in] @104
            int which = rid / 2304, r = rid % 2304;
            int i = r / 24, o4 = r % 24;
            const float* src = which == 0 ? qw : which == 1 ? kw : which == 2 ? vw : pw;
            float4 u = *(const float4*)(src + i * 96 + 4 * o4);
            bf16_t* dst = (bf16_t*)(ws + WS_WQ + which * 19968);
            dst[(4 * o4 + 0) * LDC + i] = (bf16_t)u.x;
            dst[(4 * o4 + 1) * LDC + i] = (bf16_t)u.y;
            dst[(4 * o4 + 2) * LDC + i] = (bf16_t)u.z;
            dst[(4 * o4 + 3) * LDC + i] = (bf16_t)u.w;
        } else if (rid < 18432) {                    // fc1: [96][384] -> [384][100]
            int r = rid - 9216;
            int i = r / 96, m4 = r % 96;
            float4 u = *(const float4*)(fc1w + i * 384 + 4 * m4);
            bf16_t* dst = (bf16_t*)(ws + WS_FC1);
            dst[(4 * m4 + 0) * LDW + i] = (bf16_t)u.x;
            dst[(4 * m4 + 1) * LDW + i] = (bf16_t)u.y;
            dst[(4 * m4 + 2) * LDW + i] = (bf16_t)u.z;
            dst[(4 * m4 + 3) * LDW + i] = (bf16_t)u.w;
        } else {                                     // fc2: [384][96] -> [4][96 out][96 mid] @100
            int r = rid - 18432;                     // 0..9215
            int g = r / 24, o4 = r % 24;             // g = global mid 0..383
            int ch = g / 96, m = g % 96;
            float4 u = *(const float4*)(fc2w + g * 96 + 4 * o4);
            bf16_t* dst = (bf16_t*)(ws + WS_FC2);
            dst[(ch * 96 + 4 * o4 + 0) * LDW + m] = (bf16_t)u.x;
            dst[(ch * 96 + 4 * o4 + 1) * LDW + m] = (bf16_t)u.y;
            dst[(ch * 96 + 4 * o4 + 2) * LDW + m] = (bf16_t)u.z;
            dst[(ch * 96 + 4 * o4 + 3) * LDW + m] = (bf16_t)u.w;
        }
    } else {
        int e = (blockIdx.x - 54) * 512 + tid;       // 0..12287 (h, row n, col m)
        if (e < 12288) {
            const float* tbl = (const float*)(ws + WS_TBL);
            float* bias = (float*)(ws + WS_BIAS);
            int h = e >> 12, nm = e & 4095, n = nm >> 6, m = nm & 63;
            int dr = (n >> 3) - (m >> 3) + 7, dc = (n & 7) - (m & 7) + 7;
            float t = tbl[(dr * 15 + dc) * 3 + h];
            // f4-transposed layout: [h][row][m&15][m>>4]
            bias[(h << 12) | (n << 6) | ((m & 15) << 2) | (m >> 4)] = 16.f / (1.f + __expf(-t));
        }
    }
}

// ---------------- Kernel A: fused window attention -> hs (into d_out) ----------------
// Verbatim R6 structure (passed full graph timing): LDS 40704, bounds (256,3).
__global__ __launch_bounds__(256, 3) void kA_attn(
    const float* __restrict__ hidden, const float* __restrict__ tv,
    const float* __restrict__ qb, const float* __restrict__ vb,
    const float* __restrict__ pb, const float* __restrict__ lsc,
    const float* __restrict__ lnww, const float* __restrict__ lnwb,
    const float* __restrict__ lnbw, const float* __restrict__ lnbb,
    const char* __restrict__ ws, float* __restrict__ hs)
{
    __shared__ __align__(16) char sm[40704];
    bf16_t* vT   = (bf16_t*)(sm + 0);         // [96][72]   = 13824
    bf16_t* qn   = (bf16_t*)(sm + 13824);     // [64][104]  = 13312
    bf16_t* kn   = (bf16_t*)(sm + 27136);     // [64][104]  = 13312
    bf16_t* P    = (bf16_t*)(sm + 13824);     // [3][64][70], overlays qn+kn (after B2)
    bf16_t* ctxb = (bf16_t*)(sm + 0);         // [64][104], overlays vT (after B4)

    const int tid = threadIdx.x;
    const int wv = tid >> 6, lane = tid & 63, lg = lane >> 4, lr = lane & 15;
    const int wid = blockIdx.x;
    const int bat = wid >> 10, wim = wid & 1023, hw = wim >> 5, wwi = wim & 31;

    // ---- phase 1: QKV ----
    {
        bf16x8 af[3];
        {
            int tok = 16 * wv + lr;
            int gr = ((hw << 3) + (tok >> 3) + 4) & 255;
            int gc = ((wwi << 3) + (tok & 7) + 4) & 255;
            const float* xb = hidden + (((size_t)bat << 16) + (gr << 8) + gc) * 96;
            #pragma unroll
            for (int ks = 0; ks < 3; ++ks) {
                float4 u0 = *(const float4*)(xb + 32 * ks + 8 * lg);
                float4 u1 = *(const float4*)(xb + 32 * ks + 8 * lg + 4);
                bf16x8 f;
                f[0] = (bf16_t)u0.x; f[1] = (bf16_t)u0.y; f[2] = (bf16_t)u0.z; f[3] = (bf16_t)u0.w;
                f[4] = (bf16_t)u1.x; f[5] = (bf16_t)u1.y; f[6] = (bf16_t)u1.z; f[7] = (bf16_t)u1.w;
                af[ks] = f;
            }
        }
        const bf16_t* Wq = (const bf16_t*)(ws + WS_WQ);
        const bf16_t* Wk = (const bf16_t*)(ws + WS_WK);
        const bf16_t* Wv = (const bf16_t*)(ws + WS_WV);

        {   // Q
            bf16x8 wf[6][3];
            #pragma unroll
            for (int n = 0; n < 6; ++n)
                #pragma unroll
                for (int ks = 0; ks < 3; ++ks)
                    wf[n][ks] = *(const bf16x8*)(Wq + (16 * n + lr) * LDC + 32 * ks + 8 * lg);
            f32x4 acc[6];
            #pragma unroll
            for (int n = 0; n < 6; ++n) {
                f32x4 a = {0.f,0.f,0.f,0.f};
                #pragma unroll
                for (int ks = 0; ks < 3; ++ks) a = mfma16(af[ks], wf[n][ks], a);
                float bq = qb[16 * n + lr];
                #pragma unroll
                for (int j = 0; j < 4; ++j) a[j] += bq;
                acc[n] = a;
            }
            #pragma unroll
            for (int h = 0; h < 3; ++h)
                #pragma unroll
                for (int j = 0; j < 4; ++j) {
                    float s = acc[2*h][j] * acc[2*h][j] + acc[2*h+1][j] * acc[2*h+1][j];
                    s += __shfl_xor(s, 1); s += __shfl_xor(s, 2); s += __shfl_xor(s, 4); s += __shfl_xor(s, 8);
                    float inv = 1.f / fmaxf(sqrtf(s), 1e-12f);
                    int row = 16 * wv + 4 * lg + j;
                    qn[row * LDC + 32 * h + lr]      = (bf16_t)(acc[2*h][j] * inv);
                    qn[row * LDC + 32 * h + 16 + lr] = (bf16_t)(acc[2*h+1][j] * inv);
                }
        }
        {   // K
            bf16x8 wf[6][3];
            #pragma unroll
            for (int n = 0; n < 6; ++n)
                #pragma unroll
                for (int ks = 0; ks < 3; ++ks)
                    wf[n][ks] = *(const bf16x8*)(Wk + (16 * n + lr) * LDC + 32 * ks + 8 * lg);
            f32x4 acc[6];
            #pragma unroll
            for (int n = 0; n < 6; ++n) {
                f32x4 a = {0.f,0.f,0.f,0.f};
                #pragma unroll
                for (int ks = 0; ks < 3; ++ks) a = mfma16(af[ks], wf[n][ks], a);
                acc[n] = a;
            }
            #pragma unroll
            for (int h = 0; h < 3; ++h)
                #pragma unroll
                for (int j = 0; j < 4; ++j) {
                    float s = acc[2*h][j] * acc[2*h][j] + acc[2*h+1][j] * acc[2*h+1][j];
                    s += __shfl_xor(s, 1); s += __shfl_xor(s, 2); s += __shfl_xor(s, 4); s += __shfl_xor(s, 8);
                    float inv = 1.f / fmaxf(sqrtf(s), 1e-12f);
                    int row = 16 * wv + 4 * lg + j;
                    kn[row * LDC + 32 * h + lr]      = (bf16_t)(acc[2*h][j] * inv);
                    kn[row * LDC + 32 * h + 16 + lr] = (bf16_t)(acc[2*h+1][j] * inv);
                }
        }
        {   // V (store transposed)
            bf16x8 wf[6][3];
            #pragma unroll
            for (int n = 0; n < 6; ++n)
                #pragma unroll
                for (int ks = 0; ks < 3; ++ks)
                    wf[n][ks] = *(const bf16x8*)(Wv + (16 * n + lr) * LDC + 32 * ks + 8 * lg);
            #pragma unroll
            for (int n = 0; n < 6; ++n) {
                f32x4 a = {0.f,0.f,0.f,0.f};
                #pragma unroll
                for (int ks = 0; ks < 3; ++ks) a = mfma16(af[ks], wf[n][ks], a);
                float bv_ = vb[16 * n + lr];
                bf16x4 pk;
                #pragma unroll
                for (int j = 0; j < 4; ++j) pk[j] = (bf16_t)(a[j] + bv_);
                *(bf16x4*)(vT + (16 * n + lr) * LDT + 16 * wv + 4 * lg) = pk;
            }
        }
    }
    __syncthreads();                                         // B1

    // ---- phase 2: S = qn@kn^T (+bias+mask), softmax, write P ----
    {
        float br[3][4][4];
        const float* biasT = (const float*)(ws + WS_BIAS);
        #pragma unroll
        for (int h = 0; h < 3; ++h)
            #pragma unroll
            for (int j = 0; j < 4; ++j) {
                float4 u = *(const float4*)(biasT + (h << 12) + ((16 * wv + 4 * lg + j) << 6) + (lr << 2));
                br[h][0][j] = u.x; br[h][1][j] = u.y; br[h][2][j] = u.z; br[h][3][j] = u.w;
            }

        f32x4 s[3][4];
        #pragma unroll
        for (int h = 0; h < 3; ++h) {
            bf16x8 aq = *(const bf16x8*)(qn + (16 * wv + lr) * LDC + 32 * h + 8 * lg);
            bf16x8 bk[4];
            #pragma unroll
            for (int f = 0; f < 4; ++f)
                bk[f] = *(const bf16x8*)(kn + (16 * f + lr) * LDC + 32 * h + 8 * lg);
            #pragma unroll
            for (int f = 0; f < 4; ++f) {
                f32x4 z = {0.f,0.f,0.f,0.f};
                s[h][f] = mfma16(aq, bk[f], z);
            }
        }
        __syncthreads();                                     // B2

        float ls[3];
        #pragma unroll
        for (int h = 0; h < 3; ++h) ls[h] = __expf(fminf(lsc[h], 4.6051702f));
        int cntm[4], cnti[4];
        #pragma unroll
        for (int f = 0; f < 4; ++f) cntm[f] = regcnt(16 * f + lr, hw, wwi);
        #pragma unroll
        for (int j = 0; j < 4; ++j) cnti[j] = regcnt(16 * wv + 4 * lg + j, hw, wwi);
        #pragma unroll
        for (int h = 0; h < 3; ++h) {
            #pragma unroll
            for (int f = 0; f < 4; ++f)
                #pragma unroll
                for (int j = 0; j < 4; ++j) {
                    float mk = (cnti[j] != cntm[f]) ? -100.f : 0.f;
                    s[h][f][j] = fmaf(s[h][f][j], ls[h], br[h][f][j] + mk);
                }
            #pragma unroll
            for (int j = 0; j < 4; ++j) {
                float mx = fmaxf(fmaxf(s[h][0][j], s[h][1][j]), fmaxf(s[h][2][j], s[h][3][j]));
                mx = fmaxf(mx, __shfl_xor(mx, 1)); mx = fmaxf(mx, __shfl_xor(mx, 2));
                mx = fmaxf(mx, __shfl_xor(mx, 4)); mx = fmaxf(mx, __shfl_xor(mx, 8));
                float sum = 0.f;
                #pragma unroll
                for (int f = 0; f < 4; ++f) { float e = __expf(s[h][f][j] - mx); s[h][f][j] = e; sum += e; }
                sum += __shfl_xor(sum, 1); sum += __shfl_xor(sum, 2); sum += __shfl_xor(sum, 4); sum += __shfl_xor(sum, 8);
                float inv = 1.f / sum;
                int row = 16 * wv + 4 * lg + j;
                #pragma unroll
                for (int f = 0; f < 4; ++f)
                    P[h * 64 * LDP + row * LDP + 16 * f + lr] = (bf16_t)(s[h][f][j] * inv);
            }
        }
    }
    __syncthreads();                                         // B3

    // ---- phase 3: ctx = P@V ----
    {
        f32x4 ctx[6];
        #pragma unroll
        for (int t = 0; t < 6; ++t) { f32x4 z = {0.f,0.f,0.f,0.f}; ctx[t] = z; }
        bf16x8 ap[3][2], bv2[3][2][2];
        #pragma unroll
        for (int h = 0; h < 3; ++h)
            #pragma unroll
            for (int ks = 0; ks < 2; ++ks) {
                ap[h][ks] = *(const bf16x8*)(P + h * 64 * LDP + (16 * wv + lr) * LDP + 32 * ks + 8 * lg);
                #pragma unroll
                for (int dt = 0; dt < 2; ++dt)
                    bv2[h][dt][ks] = *(const bf16x8*)(vT + (32 * h + 16 * dt + lr) * LDT + 32 * ks + 8 * lg);
            }
        #pragma unroll
        for (int h = 0; h < 3; ++h)
            #pragma unroll
            for (int ks = 0; ks < 2; ++ks)
                #pragma unroll
                for (int dt = 0; dt < 2; ++dt)
                    ctx[2 * h + dt] = mfma16(ap[h][ks], bv2[h][dt][ks], ctx[2 * h + dt]);
        __syncthreads();                                     // B4
        #pragma unroll
        for (int t = 0; t < 6; ++t)
            #pragma unroll
            for (int j = 0; j < 4; ++j)
                ctxb[(16 * wv + 4 * lg + j) * LDC + 16 * t + lr] = (bf16_t)ctx[t][j];
    }
    __syncthreads();                                         // B5

    // ---- phase 4: proj + conditional LN + residual -> hs ----
    {
        const bf16_t* Wp = (const bf16_t*)(ws + WS_WP);
        bf16x8 wf[6][3];
        #pragma unroll
        for (int n = 0; n < 6; ++n)
            #pragma unroll
            for (int ks = 0; ks < 3; ++ks)
                wf[n][ks] = *(const bf16x8*)(Wp + (16 * n + lr) * LDC + 32 * ks + 8 * lg);
        bf16x8 af[3];
        #pragma unroll
        for (int ks = 0; ks < 3; ++ks) af[ks] = *(const bf16x8*)(ctxb + (16 * wv + lr) * LDC + 32 * ks + 8 * lg);
        f32x4 acc[6];
        #pragma unroll
        for (int n = 0; n < 6; ++n) {
            f32x4 a = {0.f,0.f,0.f,0.f};
            #pragma unroll
            for (int ks = 0; ks < 3; ++ks) a = mfma16(af[ks], wf[n][ks], a);
            float bp = pb[16 * n + lr];
            #pragma unroll
            for (int j = 0; j < 4; ++j) a[j] += bp;
            acc[n] = a;
        }
        float tb = tv[bat];
        float wco[6], bco[6];
        #pragma unroll
        for (int t = 0; t < 6; ++t) {
            int col = 16 * t + lr;
            wco[t] = fmaf(tb, lnww[col], lnwb[col]);
            bco[t] = fmaf(tb, lnbw[col], lnbb[col]);
        }
        #pragma unroll
        for (int j = 0; j < 4; ++j) {
            float smn = 0.f, sq = 0.f;
            #pragma unroll
            for (int t = 0; t < 6; ++t) { float v = acc[t][j]; smn += v; sq = fmaf(v, v, sq); }
            smn += __shfl_xor(smn, 1); smn += __shfl_xor(smn, 2); smn += __shfl_xor(smn, 4); smn += __shfl_xor(smn, 8);
            sq  += __shfl_xor(sq, 1);  sq  += __shfl_xor(sq, 2);  sq  += __shfl_xor(sq, 4);  sq  += __shfl_xor(sq, 8);
            float mean = smn * (1.f / 96.f);
            float var  = sq * (1.f / 96.f) - mean * mean;
            float rstd = rsqrtf(var + 1e-5f);
            int trow = 16 * wv + 4 * lg + j;
            int gr = ((hw << 3) + (trow >> 3) + 4) & 255;
            int gc = ((wwi << 3) + (trow & 7) + 4) & 255;
            size_t gbase = (((size_t)bat << 16) + (gr << 8) + gc) * 96;
            float hid[6];
            #pragma unroll
            for (int t = 0; t < 6; ++t) hid[t] = hidden[gbase + 16 * t + lr];
            #pragma unroll
            for (int t = 0; t < 6; ++t) {
                float xn = (acc[t][j] - mean) * rstd;
                hs[gbase + 16 * t + lr] = hid[t] + fmaf(wco[t], xn, bco[t]);
            }
        }
    }
}

// ---------------- Kernel B: MLP + conditional LN + residual (in-place on d_out) ----------------
// 256 thr, 128 tokens/block, 1024 blocks. Per chunk: cooperative 38.4 KB weight stage,
// fc1 -> gelu -> gbuf, barrier, fc2 accumulate. LDS 65,024 -> 2 blocks/CU. ~110 VGPR live.
__global__ __launch_bounds__(256, 2) void kB_mlp(
    const float* __restrict__ tv, const float* __restrict__ fc1b,
    const float* __restrict__ fc2b,
    const float* __restrict__ lnww, const float* __restrict__ lnwb,
    const float* __restrict__ lnbw, const float* __restrict__ lnbb,
    const char* __restrict__ ws, float* __restrict__ io)
{
    __shared__ __align__(16) char smem[65024];
    bf16_t* w1c  = (bf16_t*)(smem + 0);       // [96][100] current fc1 chunk (mid rows)
    bf16_t* w2c  = (bf16_t*)(smem + 19200);   // [96][100] current fc2 chunk (out rows, mid cols)
    bf16_t* gbuf = (bf16_t*)(smem + 38400);   // [128][104] gelu output

    const int tid = threadIdx.x;
    const int wv = tid >> 6, lane = tid & 63, lg = lane >> 4, lr = lane & 15;
    const int tblk = blockIdx.x * 128;
    const float tb = tv[tblk >> 16];

    // A-fragments of hs (rows 32wv+16mt+lr), loaded once, reused across all 4 chunks
    bf16x8 af[2][3];
    #pragma unroll
    for (int mt = 0; mt < 2; ++mt) {
        const float* hb = io + (size_t)(tblk + 32 * wv + 16 * mt + lr) * 96;
        #pragma unroll
        for (int ks = 0; ks < 3; ++ks) {
            float4 u0 = *(const float4*)(hb + 32 * ks + 8 * lg);
            float4 u1 = *(const float4*)(hb + 32 * ks + 8 * lg + 4);
            bf16x8 f;
            f[0] = (bf16_t)u0.x; f[1] = (bf16_t)u0.y; f[2] = (bf16_t)u0.z; f[3] = (bf16_t)u0.w;
            f[4] = (bf16_t)u1.x; f[5] = (bf16_t)u1.y; f[6] = (bf16_t)u1.z; f[7] = (bf16_t)u1.w;
            af[mt][ks] = f;
        }
    }

    f32x4 mlp[2][6];
    #pragma unroll
    for (int mt = 0; mt < 2; ++mt)
        #pragma unroll
        for (int ot = 0; ot < 6; ++ot) { f32x4 z = {0.f,0.f,0.f,0.f}; mlp[mt][ot] = z; }

    #pragma unroll 1
    for (int ch = 0; ch < 4; ++ch) {
        if (ch) __syncthreads();                 // prev chunk's w1c/w2c reads complete
        {   // cooperative stage: w1 chunk + w2 chunk (2 x 19,200 B), float4-coalesced
            const float4* s1 = (const float4*)(ws + WS_FC1 + ch * 19200);
            const float4* s2 = (const float4*)(ws + WS_FC2 + ch * 19200);
            float4* d1 = (float4*)w1c;
            float4* d2 = (float4*)w2c;
            #pragma unroll
            for (int i = 0; i < 5; ++i) {
                int idx = tid + 256 * i;
                if (idx < 1200) { d1[idx] = s1[idx]; d2[idx] = s2[idx]; }
            }
        }
        __syncthreads();                         // staged chunk visible

        // fc1 + gelu -> gbuf
        #pragma unroll
        for (int nt = 0; nt < 6; ++nt) {
            bf16x8 b1[3];
            #pragma unroll
            for (int ks = 0; ks < 3; ++ks)
                b1[ks] = *(const bf16x8*)(w1c + (16 * nt + lr) * LDW + 32 * ks + 8 * lg);
            float bb = fc1b[96 * ch + 16 * nt + lr];
            #pragma unroll
            for (int mt = 0; mt < 2; ++mt) {
                f32x4 a = {0.f,0.f,0.f,0.f};
                #pragma unroll
                for (int ks = 0; ks < 3; ++ks) a = mfma16(af[mt][ks], b1[ks], a);
                #pragma unroll
                for (int j = 0; j < 4; ++j) {
                    float x = a[j] + bb;
                    float u = 0.7978845608f * fmaf(0.044715f * x, x * x, x);
                    float t = __expf(2.f * u);
                    float g = x - x * __builtin_amdgcn_rcpf(t + 1.f);
                    gbuf[(32 * wv + 16 * mt + 4 * lg + j) * LDC + 16 * nt + lr] = (bf16_t)g;
                }
            }
        }
        __syncthreads();                         // gbuf visible (defensive)

        // fc2 accumulate
        #pragma unroll
        for (int kk = 0; kk < 3; ++kk) {
            bf16x8 gf[2];
            #pragma unroll
            for (int mt = 0; mt < 2; ++mt)
                gf[mt] = *(const bf16x8*)(gbuf + (32 * wv + 16 * mt + lr) * LDC + 32 * kk + 8 * lg);
            #pragma unroll
            for (int oh = 0; oh < 2; ++oh) {
                bf16x8 a2[3];
                #pragma unroll
                for (int o3 = 0; o3 < 3; ++o3)
                    a2[o3] = *(const bf16x8*)(w2c + (16 * (3 * oh + o3) + lr) * LDW + 32 * kk + 8 * lg);
                #pragma unroll
                for (int mt = 0; mt < 2; ++mt)
                    #pragma unroll
                    for (int o3 = 0; o3 < 3; ++o3)
                        mlp[mt][3 * oh + o3] = mfma16(gf[mt], a2[o3], mlp[mt][3 * oh + o3]);
            }
        }
    }

    // epilogue: fc2 bias + conditional LN + residual, per M-tile
    float wco[6], bco[6];
    #pragma unroll
    for (int ot = 0; ot < 6; ++ot) {
        int col = 16 * ot + lr;
        wco[ot] = fmaf(tb, lnww[col], lnwb[col]);
        bco[ot] = fmaf(tb, lnbw[col], lnbb[col]);
    }
    #pragma unroll
    for (int mt = 0; mt < 2; ++mt) {
        #pragma unroll
        for (int ot = 0; ot < 6; ++ot) {
            float bb = fc2b[16 * ot + lr];
            #pragma unroll
            for (int j = 0; j < 4; ++j) mlp[mt][ot][j] += bb;
        }
        #pragma unroll
        for (int j = 0; j < 4; ++j) {
            float smn = 0.f, sq = 0.f;
            #pragma unroll
            for (int ot = 0; ot < 6; ++ot) { float v = mlp[mt][ot][j]; smn += v; sq = fmaf(v, v, sq); }
            smn += __shfl_xor(smn, 1); smn += __shfl_xor(smn, 2); smn += __shfl_xor(smn, 4); smn += __shfl_xor(smn, 8);
            sq  += __shfl_xor(sq, 1);  sq  += __shfl_xor(sq, 2);  sq  += __shfl_xor(sq, 4);  sq  += __shfl_xor(sq, 8);
            float mean = smn * (1.f / 96.f);
            float var  = sq * (1.f / 96.f) - mean * mean;
            float rstd = rsqrtf(var + 1e-5f);
            size_t row = (size_t)tblk + 32 * wv + 16 * mt + 4 * lg + j;
            float hid[6];
            #pragma unroll
            for (int ot = 0; ot < 6; ++ot) hid[ot] = io[row * 96 + 16 * ot + lr];
            #pragma unroll
            for (int ot = 0; ot < 6; ++ot) {
                float xn = (mlp[mt][ot][j] - mean) * rstd;
                io[row * 96 + 16 * ot + lr] = hid[ot] + fmaf(wco[ot], xn, bco[ot]);
            }
        }
    }
}

extern "C" void kernel_launch(void* const* d_in, const int* in_sizes, int n_in,
                              void* d_out, int out_size, void* d_ws, size_t ws_size,
                              hipStream_t stream)
{
    const float* hidden = (const float*)d_in[0];
    const float* tv     = (const float*)d_in[1];
    const float* q_w    = (const float*)d_in[2];
    const float* q_b    = (const float*)d_in[3];
    const float* k_w    = (const float*)d_in[4];
    const float* v_w    = (const float*)d_in[5];
    const float* v_b    = (const float*)d_in[6];
    const float* p_w    = (const float*)d_in[7];
    const float* p_b    = (const float*)d_in[8];
    const float* lsc    = (const float*)d_in[9];
    const float* cw1    = (const float*)d_in[10];
    const float* cb1    = (const float*)d_in[11];
    const float* cw2    = (const float*)d_in[12];
    const float* lnb_ww = (const float*)d_in[13];
    const float* lnb_wb = (const float*)d_in[14];
    const float* lnb_bw = (const float*)d_in[15];
    const float* lnb_bb = (const float*)d_in[16];
    const float* lna_ww = (const float*)d_in[17];
    const float* lna_wb = (const float*)d_in[18];
    const float* lna_bw = (const float*)d_in[19];
    const float* lna_bb = (const float*)d_in[20];
    const float* fc1_w  = (const float*)d_in[21];
    const float* fc1_b  = (const float*)d_in[22];
    const float* fc2_w  = (const float*)d_in[23];
    const float* fc2_b  = (const float*)d_in[24];
    char* ws = (char*)d_ws;
    float* out = (float*)d_out;

    k0a_cpb<<<dim3(57), dim3(256), 0, stream>>>(cw1, cb1, cw2, ws);
    k0w_prep<<<dim3(78), dim3(512), 0, stream>>>(q_w, k_w, v_w, p_w, fc1_w, fc2_w, ws);
    kA_attn<<<dim3(2048), dim3(256), 0, stream>>>(hidden, tv, q_b, v_b, p_b, lsc,
                                                  lnb_ww, lnb_wb, lnb_bw, lnb_bb, ws, out);
    kB_mlp<<<dim3(1024), dim3(256), 0, stream>>>(tv, fc1_b, fc2_b,
                                                 lna_ww, lna_wb, lna_bw, lna_bb, ws, out);
}

// Round 10
// 270.322 us; speedup vs baseline: 1.7343x; 1.0852x over previous
//
#include <hip/hip_runtime.h>
#include <hip/hip_bf16.h>

typedef __bf16 bf16_t;
typedef bf16_t bf16x8 __attribute__((ext_vector_type(8)));
typedef bf16_t bf16x4 __attribute__((ext_vector_type(4)));
typedef float  f32x4  __attribute__((ext_vector_type(4)));

#define LDC 104   // stride (bf16 elems) for 96-wide qkvp tiles + gbuf/hsb
#define LDW 100   // stride for fc1/fc2 weight tiles
#define LDT 72    // stride for vT token dim
#define LDP 70    // stride for P token dim

// ws layout (bytes) — identical to R9 (verified footprint 285,324 B)
#define WS_WQ    0
#define WS_WK    19968
#define WS_WV    39936
#define WS_WP    59904
#define WS_FC1   79872      // [384][100] bf16
#define WS_FC2   156672     // [4][96][100] bf16 (chunk ch = [96 out][96 mid])
#define WS_BIAS  233472     // [3][64 row][16 lr][4 f] f32
#define WS_TBL   282624     // [225][3] f32 raw cpb table

__device__ __forceinline__ f32x4 mfma16(bf16x8 a, bf16x8 b, f32x4 c) {
    return __builtin_amdgcn_mfma_f32_16x16x32_bf16(a, b, c, 0, 0, 0);
}

__device__ __forceinline__ float cpbf(int v) {   // v in -7..7
    float x = (float)v * (8.0f / 7.0f);
    float l = log2f(fabsf(x) + 1.0f) * (1.0f / 3.0f);
    return x < 0.f ? -l : l;
}

__device__ __forceinline__ int regcnt(int t, int hw, int ww) {
    int r = t >> 3, c = t & 7;
    int rr = (hw == 31) ? (r < 4 ? 1 : 2) : 0;
    int cc = (ww == 31) ? (c < 4 ? 1 : 2) : 0;
    return rr * 3 + cc;
}

// ---------------- k0a: CPB table — one WAVE per entry ----------------
__global__ __launch_bounds__(256) void k0a_cpb(
    const float* __restrict__ cw1, const float* __restrict__ cb1,
    const float* __restrict__ cw2, char* __restrict__ ws)
{
    const int wv = threadIdx.x >> 6, lane = threadIdx.x & 63;
    const int e = blockIdx.x * 4 + wv;
    if (e >= 225) return;
    int ia = e / 15, ib = e % 15;
    float c0 = cpbf(ia - 7), c1 = cpbf(ib - 7);
    float a0 = 0.f, a1 = 0.f, a2 = 0.f;
    #pragma unroll
    for (int c = 0; c < 8; ++c) {
        int j = c * 64 + lane;
        float h = fmaf(c0, cw1[j], fmaf(c1, cw1[512 + j], cb1[j]));
        h = fmaxf(h, 0.f);
        a0 = fmaf(h, cw2[j * 3 + 0], a0);
        a1 = fmaf(h, cw2[j * 3 + 1], a1);
        a2 = fmaf(h, cw2[j * 3 + 2], a2);
    }
    #pragma unroll
    for (int m = 1; m < 64; m <<= 1) {
        a0 += __shfl_xor(a0, m);
        a1 += __shfl_xor(a1, m);
        a2 += __shfl_xor(a2, m);
    }
    if (lane == 0) {
        float* tbl = (float*)(ws + WS_TBL);
        tbl[e * 3 + 0] = a0; tbl[e * 3 + 1] = a1; tbl[e * 3 + 2] = a2;
    }
}

// ---------------- k0w: weight repack (blocks 0..53) + bias expand (blocks 54..77) ----------------
__global__ __launch_bounds__(512) void k0w_prep(
    const float* __restrict__ qw, const float* __restrict__ kw,
    const float* __restrict__ vw, const float* __restrict__ pw,
    const float* __restrict__ fc1w, const float* __restrict__ fc2w,
    char* __restrict__ ws)
{
    int tid = threadIdx.x;
    if (blockIdx.x < 54) {
        int rid = blockIdx.x * 512 + tid;            // 0..27647, float4-coalesced reads
        if (rid < 9216) {                            // q,k,v,proj: [96 in][96 out] -> [out][in] @104
            int which = rid / 2304, r = rid % 2304;
            int i = r / 24, o4 = r % 24;
            const float* src = which == 0 ? qw : which == 1 ? kw : which == 2 ? vw : pw;
            float4 u = *(const float4*)(src + i * 96 + 4 * o4);
            bf16_t* dst = (bf16_t*)(ws + WS_WQ + which * 19968);
            dst[(4 * o4 + 0) * LDC + i] = (bf16_t)u.x;
            dst[(4 * o4 + 1) * LDC + i] = (bf16_t)u.y;
            dst[(4 * o4 + 2) * LDC + i] = (bf16_t)u.z;
            dst[(4 * o4 + 3) * LDC + i] = (bf16_t)u.w;
        } else if (rid < 18432) {                    // fc1: [96][384] -> [384][100]
            int r = rid - 9216;
            int i = r / 96, m4 = r % 96;
            float4 u = *(const float4*)(fc1w + i * 384 + 4 * m4);
            bf16_t* dst = (bf16_t*)(ws + WS_FC1);
            dst[(4 * m4 + 0) * LDW + i] = (bf16_t)u.x;
            dst[(4 * m4 + 1) * LDW + i] = (bf16_t)u.y;
            dst[(4 * m4 + 2) * LDW + i] = (bf16_t)u.z;
            dst[(4 * m4 + 3) * LDW + i] = (bf16_t)u.w;
        } else {                                     // fc2: [384][96] -> [4][96 out][96 mid] @100
            int r = rid - 18432;                     // 0..9215
            int g = r / 24, o4 = r % 24;             // g = global mid 0..383
            int ch = g / 96, m = g % 96;
            float4 u = *(const float4*)(fc2w + g * 96 + 4 * o4);
            bf16_t* dst = (bf16_t*)(ws + WS_FC2);
            dst[(ch * 96 + 4 * o4 + 0) * LDW + m] = (bf16_t)u.x;
            dst[(ch * 96 + 4 * o4 + 1) * LDW + m] = (bf16_t)u.y;
            dst[(ch * 96 + 4 * o4 + 2) * LDW + m] = (bf16_t)u.z;
            dst[(ch * 96 + 4 * o4 + 3) * LDW + m] = (bf16_t)u.w;
        }
    } else {
        int e = (blockIdx.x - 54) * 512 + tid;       // 0..12287 (h, row n, col m)
        if (e < 12288) {
            const float* tbl = (const float*)(ws + WS_TBL);
            float* bias = (float*)(ws + WS_BIAS);
            int h = e >> 12, nm = e & 4095, n = nm >> 6, m = nm & 63;
            int dr = (n >> 3) - (m >> 3) + 7, dc = (n & 7) - (m & 7) + 7;
            float t = tbl[(dr * 15 + dc) * 3 + h];
            bias[(h << 12) | (n << 6) | ((m & 15) << 2) | (m >> 4)] = 16.f / (1.f + __expf(-t));
        }
    }
}

// ---------------- Fused kernel: window attention + CLN + MLP + CLN -> out ----------------
// One block per 64-token window. hs never materialized: kept in regs (residual) +
// wave-private LDS band (MLP A-frags). MLP adds zero barriers.
__global__ __launch_bounds__(256, 3) void kAB(
    const float* __restrict__ hidden, const float* __restrict__ tv,
    const float* __restrict__ qb, const float* __restrict__ vb,
    const float* __restrict__ pb, const float* __restrict__ lsc,
    const float* __restrict__ lnbww, const float* __restrict__ lnbwb,
    const float* __restrict__ lnbbw, const float* __restrict__ lnbbb,
    const float* __restrict__ lnaww, const float* __restrict__ lnawb,
    const float* __restrict__ lnabw, const float* __restrict__ lnabb,
    const float* __restrict__ fc1b, const float* __restrict__ fc2b,
    const char* __restrict__ ws, float* __restrict__ out)
{
    __shared__ __align__(16) char sm[40704];
    bf16_t* vT   = (bf16_t*)(sm + 0);         // [96][72]   = 13824
    bf16_t* qn   = (bf16_t*)(sm + 13824);     // [64][104]  = 13312
    bf16_t* kn   = (bf16_t*)(sm + 27136);     // [64][104]  = 13312
    bf16_t* P    = (bf16_t*)(sm + 13824);     // [3][64][70] = 26880, overlays qn+kn (after B2)
    bf16_t* ctxb = (bf16_t*)(sm + 0);         // [64][104], overlays vT (after B4)
    bf16_t* gbuf = (bf16_t*)(sm + 13824);     // [64][104], overlays P head (after B5)
    bf16_t* hsb  = (bf16_t*)(sm + 27136);     // [64][104], overlays P tail (after B5)

    const int tid = threadIdx.x;
    const int wv = tid >> 6, lane = tid & 63, lg = lane >> 4, lr = lane & 15;
    const int wid = blockIdx.x;
    const int bat = wid >> 10, wim = wid & 1023, hw = wim >> 5, wwi = wim & 31;

    // ---- phase 1: QKV ----
    {
        bf16x8 af[3];
        {
            int tok = 16 * wv + lr;
            int gr = ((hw << 3) + (tok >> 3) + 4) & 255;
            int gc = ((wwi << 3) + (tok & 7) + 4) & 255;
            const float* xb = hidden + (((size_t)bat << 16) + (gr << 8) + gc) * 96;
            #pragma unroll
            for (int ks = 0; ks < 3; ++ks) {
                float4 u0 = *(const float4*)(xb + 32 * ks + 8 * lg);
                float4 u1 = *(const float4*)(xb + 32 * ks + 8 * lg + 4);
                bf16x8 f;
                f[0] = (bf16_t)u0.x; f[1] = (bf16_t)u0.y; f[2] = (bf16_t)u0.z; f[3] = (bf16_t)u0.w;
                f[4] = (bf16_t)u1.x; f[5] = (bf16_t)u1.y; f[6] = (bf16_t)u1.z; f[7] = (bf16_t)u1.w;
                af[ks] = f;
            }
        }
        const bf16_t* Wq = (const bf16_t*)(ws + WS_WQ);
        const bf16_t* Wk = (const bf16_t*)(ws + WS_WK);
        const bf16_t* Wv = (const bf16_t*)(ws + WS_WV);

        {   // Q
            bf16x8 wf[6][3];
            #pragma unroll
            for (int n = 0; n < 6; ++n)
                #pragma unroll
                for (int ks = 0; ks < 3; ++ks)
                    wf[n][ks] = *(const bf16x8*)(Wq + (16 * n + lr) * LDC + 32 * ks + 8 * lg);
            f32x4 acc[6];
            #pragma unroll
            for (int n = 0; n < 6; ++n) {
                f32x4 a = {0.f,0.f,0.f,0.f};
                #pragma unroll
                for (int ks = 0; ks < 3; ++ks) a = mfma16(af[ks], wf[n][ks], a);
                float bq = qb[16 * n + lr];
                #pragma unroll
                for (int j = 0; j < 4; ++j) a[j] += bq;
                acc[n] = a;
            }
            #pragma unroll
            for (int h = 0; h < 3; ++h)
                #pragma unroll
                for (int j = 0; j < 4; ++j) {
                    float s = acc[2*h][j] * acc[2*h][j] + acc[2*h+1][j] * acc[2*h+1][j];
                    s += __shfl_xor(s, 1); s += __shfl_xor(s, 2); s += __shfl_xor(s, 4); s += __shfl_xor(s, 8);
                    float inv = 1.f / fmaxf(sqrtf(s), 1e-12f);
                    int row = 16 * wv + 4 * lg + j;
                    qn[row * LDC + 32 * h + lr]      = (bf16_t)(acc[2*h][j] * inv);
                    qn[row * LDC + 32 * h + 16 + lr] = (bf16_t)(acc[2*h+1][j] * inv);
                }
        }
        {   // K
            bf16x8 wf[6][3];
            #pragma unroll
            for (int n = 0; n < 6; ++n)
                #pragma unroll
                for (int ks = 0; ks < 3; ++ks)
                    wf[n][ks] = *(const bf16x8*)(Wk + (16 * n + lr) * LDC + 32 * ks + 8 * lg);
            f32x4 acc[6];
            #pragma unroll
            for (int n = 0; n < 6; ++n) {
                f32x4 a = {0.f,0.f,0.f,0.f};
                #pragma unroll
                for (int ks = 0; ks < 3; ++ks) a = mfma16(af[ks], wf[n][ks], a);
                acc[n] = a;
            }
            #pragma unroll
            for (int h = 0; h < 3; ++h)
                #pragma unroll
                for (int j = 0; j < 4; ++j) {
                    float s = acc[2*h][j] * acc[2*h][j] + acc[2*h+1][j] * acc[2*h+1][j];
                    s += __shfl_xor(s, 1); s += __shfl_xor(s, 2); s += __shfl_xor(s, 4); s += __shfl_xor(s, 8);
                    float inv = 1.f / fmaxf(sqrtf(s), 1e-12f);
                    int row = 16 * wv + 4 * lg + j;
                    kn[row * LDC + 32 * h + lr]      = (bf16_t)(acc[2*h][j] * inv);
                    kn[row * LDC + 32 * h + 16 + lr] = (bf16_t)(acc[2*h+1][j] * inv);
                }
        }
        {   // V (store transposed)
            bf16x8 wf[6][3];
            #pragma unroll
            for (int n = 0; n < 6; ++n)
                #pragma unroll
                for (int ks = 0; ks < 3; ++ks)
                    wf[n][ks] = *(const bf16x8*)(Wv + (16 * n + lr) * LDC + 32 * ks + 8 * lg);
            #pragma unroll
            for (int n = 0; n < 6; ++n) {
                f32x4 a = {0.f,0.f,0.f,0.f};
                #pragma unroll
                for (int ks = 0; ks < 3; ++ks) a = mfma16(af[ks], wf[n][ks], a);
                float bv_ = vb[16 * n + lr];
                bf16x4 pk;
                #pragma unroll
                for (int j = 0; j < 4; ++j) pk[j] = (bf16_t)(a[j] + bv_);
                *(bf16x4*)(vT + (16 * n + lr) * LDT + 16 * wv + 4 * lg) = pk;
            }
        }
    }
    __syncthreads();                                         // B1

    // ---- phase 2: S = qn@kn^T (+bias+mask), softmax, write P ----
    {
        float br[3][4][4];
        const float* biasT = (const float*)(ws + WS_BIAS);
        #pragma unroll
        for (int h = 0; h < 3; ++h)
            #pragma unroll
            for (int j = 0; j < 4; ++j) {
                float4 u = *(const float4*)(biasT + (h << 12) + ((16 * wv + 4 * lg + j) << 6) + (lr << 2));
                br[h][0][j] = u.x; br[h][1][j] = u.y; br[h][2][j] = u.z; br[h][3][j] = u.w;
            }

        f32x4 s[3][4];
        #pragma unroll
        for (int h = 0; h < 3; ++h) {
            bf16x8 aq = *(const bf16x8*)(qn + (16 * wv + lr) * LDC + 32 * h + 8 * lg);
            bf16x8 bk[4];
            #pragma unroll
            for (int f = 0; f < 4; ++f)
                bk[f] = *(const bf16x8*)(kn + (16 * f + lr) * LDC + 32 * h + 8 * lg);
            #pragma unroll
            for (int f = 0; f < 4; ++f) {
                f32x4 z = {0.f,0.f,0.f,0.f};
                s[h][f] = mfma16(aq, bk[f], z);
            }
        }
        __syncthreads();                                     // B2

        float ls[3];
        #pragma unroll
        for (int h = 0; h < 3; ++h) ls[h] = __expf(fminf(lsc[h], 4.6051702f));
        int cntm[4], cnti[4];
        #pragma unroll
        for (int f = 0; f < 4; ++f) cntm[f] = regcnt(16 * f + lr, hw, wwi);
        #pragma unroll
        for (int j = 0; j < 4; ++j) cnti[j] = regcnt(16 * wv + 4 * lg + j, hw, wwi);
        #pragma unroll
        for (int h = 0; h < 3; ++h) {
            #pragma unroll
            for (int f = 0; f < 4; ++f)
                #pragma unroll
                for (int j = 0; j < 4; ++j) {
                    float mk = (cnti[j] != cntm[f]) ? -100.f : 0.f;
                    s[h][f][j] = fmaf(s[h][f][j], ls[h], br[h][f][j] + mk);
                }
            #pragma unroll
            for (int j = 0; j < 4; ++j) {
                float mx = fmaxf(fmaxf(s[h][0][j], s[h][1][j]), fmaxf(s[h][2][j], s[h][3][j]));
                mx = fmaxf(mx, __shfl_xor(mx, 1)); mx = fmaxf(mx, __shfl_xor(mx, 2));
                mx = fmaxf(mx, __shfl_xor(mx, 4)); mx = fmaxf(mx, __shfl_xor(mx, 8));
                float sum = 0.f;
                #pragma unroll
                for (int f = 0; f < 4; ++f) { float e = __expf(s[h][f][j] - mx); s[h][f][j] = e; sum += e; }
                sum += __shfl_xor(sum, 1); sum += __shfl_xor(sum, 2); sum += __shfl_xor(sum, 4); sum += __shfl_xor(sum, 8);
                float inv = 1.f / sum;
                int row = 16 * wv + 4 * lg + j;
                #pragma unroll
                for (int f = 0; f < 4; ++f)
                    P[h * 64 * LDP + row * LDP + 16 * f + lr] = (bf16_t)(s[h][f][j] * inv);
            }
        }
    }
    __syncthreads();                                         // B3

    // ---- phase 3: ctx = P@V ----
    {
        f32x4 ctx[6];
        #pragma unroll
        for (int t = 0; t < 6; ++t) { f32x4 z = {0.f,0.f,0.f,0.f}; ctx[t] = z; }
        bf16x8 ap[3][2], bv2[3][2][2];
        #pragma unroll
        for (int h = 0; h < 3; ++h)
            #pragma unroll
            for (int ks = 0; ks < 2; ++ks) {
                ap[h][ks] = *(const bf16x8*)(P + h * 64 * LDP + (16 * wv + lr) * LDP + 32 * ks + 8 * lg);
                #pragma unroll
                for (int dt = 0; dt < 2; ++dt)
                    bv2[h][dt][ks] = *(const bf16x8*)(vT + (32 * h + 16 * dt + lr) * LDT + 32 * ks + 8 * lg);
            }
        #pragma unroll
        for (int h = 0; h < 3; ++h)
            #pragma unroll
            for (int ks = 0; ks < 2; ++ks)
                #pragma unroll
                for (int dt = 0; dt < 2; ++dt)
                    ctx[2 * h + dt] = mfma16(ap[h][ks], bv2[h][dt][ks], ctx[2 * h + dt]);
        __syncthreads();                                     // B4: all P/vT reads done
        #pragma unroll
        for (int t = 0; t < 6; ++t)
            #pragma unroll
            for (int j = 0; j < 4; ++j)
                ctxb[(16 * wv + 4 * lg + j) * LDC + 16 * t + lr] = (bf16_t)ctx[t][j];
    }
    __syncthreads();                                         // B5

    // ---- phase 4: proj + CLN(before) + residual -> hsr regs + hsb (wave-private) ----
    float hsr[6][4];
    {
        const bf16_t* Wp = (const bf16_t*)(ws + WS_WP);
        bf16x8 af[3];
        #pragma unroll
        for (int ks = 0; ks < 3; ++ks) af[ks] = *(const bf16x8*)(ctxb + (16 * wv + lr) * LDC + 32 * ks + 8 * lg);
        f32x4 acc[6];
        #pragma unroll
        for (int n = 0; n < 6; ++n) {
            f32x4 a = {0.f,0.f,0.f,0.f};
            #pragma unroll
            for (int ks = 0; ks < 3; ++ks)
                a = mfma16(af[ks], *(const bf16x8*)(Wp + (16 * n + lr) * LDC + 32 * ks + 8 * lg), a);
            float bp = pb[16 * n + lr];
            #pragma unroll
            for (int j = 0; j < 4; ++j) a[j] += bp;
            acc[n] = a;
        }
        float tb = tv[bat];
        float wco[6], bco[6];
        #pragma unroll
        for (int t = 0; t < 6; ++t) {
            int col = 16 * t + lr;
            wco[t] = fmaf(tb, lnbww[col], lnbwb[col]);
            bco[t] = fmaf(tb, lnbbw[col], lnbbb[col]);
        }
        #pragma unroll
        for (int j = 0; j < 4; ++j) {
            float smn = 0.f, sq = 0.f;
            #pragma unroll
            for (int t = 0; t < 6; ++t) { float v = acc[t][j]; smn += v; sq = fmaf(v, v, sq); }
            smn += __shfl_xor(smn, 1); smn += __shfl_xor(smn, 2); smn += __shfl_xor(smn, 4); smn += __shfl_xor(smn, 8);
            sq  += __shfl_xor(sq, 1);  sq  += __shfl_xor(sq, 2);  sq  += __shfl_xor(sq, 4);  sq  += __shfl_xor(sq, 8);
            float mean = smn * (1.f / 96.f);
            float var  = sq * (1.f / 96.f) - mean * mean;
            float rstd = rsqrtf(var + 1e-5f);
            int trow = 16 * wv + 4 * lg + j;
            int gr = ((hw << 3) + (trow >> 3) + 4) & 255;
            int gc = ((wwi << 3) + (trow & 7) + 4) & 255;
            size_t gbase = (((size_t)bat << 16) + (gr << 8) + gc) * 96;
            float hid[6];
            #pragma unroll
            for (int t = 0; t < 6; ++t) hid[t] = hidden[gbase + 16 * t + lr];
            #pragma unroll
            for (int t = 0; t < 6; ++t) {
                float xn = (acc[t][j] - mean) * rstd;
                float hsv = hid[t] + fmaf(wco[t], xn, bco[t]);
                hsr[t][j] = hsv;
                hsb[trow * LDC + 16 * t + lr] = (bf16_t)hsv;   // wave-private band
            }
        }
    }
    // no barrier: hsb/gbuf handoffs are entirely within each wave's 16-row band

    // ---- phase 5: MLP (fc1 -> gelu -> fc2), weights from ws (L2) ----
    f32x4 mlp[6];
    {
        const bf16_t* w1 = (const bf16_t*)(ws + WS_FC1);
        const bf16_t* w2 = (const bf16_t*)(ws + WS_FC2);
        bf16x8 af2[3];
        #pragma unroll
        for (int ks = 0; ks < 3; ++ks)
            af2[ks] = *(const bf16x8*)(hsb + (16 * wv + lr) * LDC + 32 * ks + 8 * lg);
        #pragma unroll
        for (int t = 0; t < 6; ++t) { f32x4 z = {0.f,0.f,0.f,0.f}; mlp[t] = z; }

        #pragma unroll 1
        for (int ch = 0; ch < 4; ++ch) {
            // fc1 chunk + gelu -> gbuf (own band)
            #pragma unroll
            for (int nt = 0; nt < 6; ++nt) {
                bf16x8 b1[3];
                #pragma unroll
                for (int ks = 0; ks < 3; ++ks)
                    b1[ks] = *(const bf16x8*)(w1 + (96 * ch + 16 * nt + lr) * LDW + 32 * ks + 8 * lg);
                f32x4 a = {0.f,0.f,0.f,0.f};
                #pragma unroll
                for (int ks = 0; ks < 3; ++ks) a = mfma16(af2[ks], b1[ks], a);
                float bb = fc1b[96 * ch + 16 * nt + lr];
                #pragma unroll
                for (int j = 0; j < 4; ++j) {
                    float x = a[j] + bb;
                    float u = 0.7978845608f * fmaf(0.044715f * x, x * x, x);
                    float t2 = __expf(2.f * u);
                    float g = x - x * __builtin_amdgcn_rcpf(t2 + 1.f);
                    gbuf[(16 * wv + 4 * lg + j) * LDC + 16 * nt + lr] = (bf16_t)g;
                }
            }
            // fc2 chunk accumulate (own band; same-wave LDS ordering via lgkmcnt)
            #pragma unroll
            for (int kk = 0; kk < 3; ++kk) {
                bf16x8 gf = *(const bf16x8*)(gbuf + (16 * wv + lr) * LDC + 32 * kk + 8 * lg);
                #pragma unroll
                for (int n = 0; n < 6; ++n) {
                    bf16x8 a2 = *(const bf16x8*)(w2 + (96 * ch + 16 * n + lr) * LDW + 32 * kk + 8 * lg);
                    mlp[n] = mfma16(gf, a2, mlp[n]);
                }
            }
        }
    }

    // ---- phase 6: fc2 bias + CLN(after) + residual -> out ----
    {
        float tb = tv[bat];
        float wco[6], bco[6];
        #pragma unroll
        for (int t = 0; t < 6; ++t) {
            int col = 16 * t + lr;
            wco[t] = fmaf(tb, lnaww[col], lnawb[col]);
            bco[t] = fmaf(tb, lnabw[col], lnabb[col]);
            float bb = fc2b[col];
            #pragma unroll
            for (int j = 0; j < 4; ++j) mlp[t][j] += bb;
        }
        #pragma unroll
        for (int j = 0; j < 4; ++j) {
            float smn = 0.f, sq = 0.f;
            #pragma unroll
            for (int t = 0; t < 6; ++t) { float v = mlp[t][j]; smn += v; sq = fmaf(v, v, sq); }
            smn += __shfl_xor(smn, 1); smn += __shfl_xor(smn, 2); smn += __shfl_xor(smn, 4); smn += __shfl_xor(smn, 8);
            sq  += __shfl_xor(sq, 1);  sq  += __shfl_xor(sq, 2);  sq  += __shfl_xor(sq, 4);  sq  += __shfl_xor(sq, 8);
            float mean = smn * (1.f / 96.f);
            float var  = sq * (1.f / 96.f) - mean * mean;
            float rstd = rsqrtf(var + 1e-5f);
            int trow = 16 * wv + 4 * lg + j;
            int gr = ((hw << 3) + (trow >> 3) + 4) & 255;
            int gc = ((wwi << 3) + (trow & 7) + 4) & 255;
            size_t gbase = (((size_t)bat << 16) + (gr << 8) + gc) * 96;
            #pragma unroll
            for (int t = 0; t < 6; ++t) {
                float xn = (mlp[t][j] - mean) * rstd;
                out[gbase + 16 * t + lr] = hsr[t][j] + fmaf(wco[t], xn, bco[t]);
            }
        }
    }
}

extern "C" void kernel_launch(void* const* d_in, const int* in_sizes, int n_in,
                              void* d_out, int out_size, void* d_ws, size_t ws_size,
                              hipStream_t stream)
{
    const float* hidden = (const float*)d_in[0];
    const float* tv     = (const float*)d_in[1];
    const float* q_w    = (const float*)d_in[2];
    const float* q_b    = (const float*)d_in[3];
    const float* k_w    = (const float*)d_in[4];
    const float* v_w    = (const float*)d_in[5];
    const float* v_b    = (const float*)d_in[6];
    const float* p_w    = (const float*)d_in[7];
    const float* p_b    = (const float*)d_in[8];
    const float* lsc    = (const float*)d_in[9];
    const float* cw1    = (const float*)d_in[10];
    const float* cb1    = (const float*)d_in[11];
    const float* cw2    = (const float*)d_in[12];
    const float* lnb_ww = (const float*)d_in[13];
    const float* lnb_wb = (const float*)d_in[14];
    const float* lnb_bw = (const float*)d_in[15];
    const float* lnb_bb = (const float*)d_in[16];
    const float* lna_ww = (const float*)d_in[17];
    const float* lna_wb = (const float*)d_in[18];
    const float* lna_bw = (const float*)d_in[19];
    const float* lna_bb = (const float*)d_in[20];
    const float* fc1_w  = (const float*)d_in[21];
    const float* fc1_b  = (const float*)d_in[22];
    const float* fc2_w  = (const float*)d_in[23];
    const float* fc2_b  = (const float*)d_in[24];
    char* ws = (char*)d_ws;
    float* out = (float*)d_out;

    k0a_cpb<<<dim3(57), dim3(256), 0, stream>>>(cw1, cb1, cw2, ws);
    k0w_prep<<<dim3(78), dim3(512), 0, stream>>>(q_w, k_w, v_w, p_w, fc1_w, fc2_w, ws);
    kAB<<<dim3(2048), dim3(256), 0, stream>>>(hidden, tv, q_b, v_b, p_b, lsc,
                                              lnb_ww, lnb_wb, lnb_bw, lnb_bb,
                                              lna_ww, lna_wb, lna_bw, lna_bb,
                                              fc1_b, fc2_b, ws, out);
}